// Round 3
// baseline (626.509 us; speedup 1.0000x reference)
//
#include <hip/hip_runtime.h>
#include <math.h>

#define N_NODES 50000
#define E_RAW   1600000
#define TE      (E_RAW + N_NODES)     // 1650000 edges incl. self loops
#define TEP     (TE + 3 * N_NODES)    // 1800000: CSR padded to 4-aligned rows (upper bound)
#define F_IN    128
#define H1      4
#define F1      128                   // H1*C1
#define F2      64
#define NEG_SLOPE 0.2f
#define EPS_F   1e-16f

__device__ __forceinline__ float lrelu(float v) { return v > 0.f ? v : NEG_SLOPE * v; }

// ---------------- init: zero deg, cursor, accum ----------------
__global__ void k_init(int* __restrict__ deg, int* __restrict__ cursor,
                       unsigned long long* __restrict__ accum) {
    int i = blockIdx.x * blockDim.x + threadIdx.x;
    if (i < N_NODES) { deg[i] = 0; cursor[i] = 0; }
    if (i < F2) accum[i] = 0ULL;
}

// ---------------- layer1 matmul + attention coefs ----------------
// 16 nodes per block, 128 threads (thread = output channel). Node/k indices are
// wave-uniform -> x loads become scalar (SGPR broadcast), no LDS needed.
__global__ __launch_bounds__(128) void k_l1_mm(
    const float* __restrict__ x, const float* __restrict__ W,
    const float* __restrict__ atts, const float* __restrict__ attd,
    float* __restrict__ xw, float* __restrict__ a1s, float* __restrict__ a1d) {
    const int t = threadIdx.x;
    const int n0 = blockIdx.x * 16;    // 50000 = 16*3125, no tail
    float acc[16];
#pragma unroll
    for (int j = 0; j < 16; ++j) acc[j] = 0.f;
    for (int k4 = 0; k4 < F_IN / 4; ++k4) {
        int k = k4 * 4;
        float w0 = W[(k + 0) * F1 + t];
        float w1 = W[(k + 1) * F1 + t];
        float w2 = W[(k + 2) * F1 + t];
        float w3 = W[(k + 3) * F1 + t];
#pragma unroll
        for (int j = 0; j < 16; ++j) {
            float4 xv = ((const float4*)(x + (size_t)(n0 + j) * F_IN))[k4];
            acc[j] = fmaf(xv.x, w0, fmaf(xv.y, w1, fmaf(xv.z, w2, fmaf(xv.w, w3, acc[j]))));
        }
    }
    float ats = atts[t], atd = attd[t];
#pragma unroll
    for (int j = 0; j < 16; ++j) {
        int n = n0 + j;
        xw[(size_t)n * F1 + t] = acc[j];
        float ps = acc[j] * ats, pd = acc[j] * atd;
#pragma unroll
        for (int off = 16; off; off >>= 1) {
            ps += __shfl_down(ps, off, 32);
            pd += __shfl_down(pd, off, 32);
        }
        if ((t & 31) == 0) {
            int h = t >> 5;
            a1s[n * H1 + h] = ps;
            a1d[n * H1 + h] = pd;
        }
    }
}

// ---------------- degree count ----------------
__global__ void k_deg(const int* __restrict__ ei, int* __restrict__ deg) {
    int e = blockIdx.x * blockDim.x + threadIdx.x;
    if (e >= TE) return;
    int d = (e < E_RAW) ? ei[E_RAW + e] : (e - E_RAW);
    atomicAdd(&deg[d], 1);
}

// ---------------- exclusive scan over PADDED degrees (2-level) ----------------
__global__ __launch_bounds__(1024) void k_scan1(const int* __restrict__ deg,
                                                int* __restrict__ incl, int* __restrict__ bsum) {
    int t = threadIdx.x, g = blockIdx.x;
    int idx = g * 1024 + t;
    int v = (idx < N_NODES) ? ((deg[idx] + 3) & ~3) : 0;
    int lane = t & 63, w = t >> 6;
#pragma unroll
    for (int off = 1; off < 64; off <<= 1) {
        int u = __shfl_up(v, off, 64);
        if (lane >= off) v += u;
    }
    __shared__ int ws[16];
    if (lane == 63) ws[w] = v;
    __syncthreads();
    if (w == 0 && lane < 16) {
        int s = ws[lane];
#pragma unroll
        for (int off = 1; off < 16; off <<= 1) {
            int u = __shfl_up(s, off, 16);
            if (lane >= off) s += u;
        }
        ws[lane] = s;
    }
    __syncthreads();
    if (w > 0) v += ws[w - 1];
    if (idx < N_NODES) incl[idx] = v;
    if (t == 1023) bsum[g] = v;
}

__global__ void k_scan2(int* __restrict__ bsum, int nblk) {
    int t = threadIdx.x;
    int v = (t < nblk) ? bsum[t] : 0;
#pragma unroll
    for (int off = 1; off < 64; off <<= 1) {
        int u = __shfl_up(v, off, 64);
        if (t >= off) v += u;
    }
    if (t < nblk) bsum[t] = v;
}

__global__ __launch_bounds__(1024) void k_scan3(const int* __restrict__ incl,
                                                const int* __restrict__ bsum,
                                                int* __restrict__ rowstart) {
    int idx = blockIdx.x * 1024 + threadIdx.x;
    if (idx >= N_NODES) return;
    int off = (blockIdx.x > 0) ? bsum[blockIdx.x - 1] : 0;
    rowstart[idx + 1] = incl[idx] + off;
    if (idx == 0) rowstart[0] = 0;
}

// ---------------- scatter into padded CSR ----------------
__global__ void k_scatter(const int* __restrict__ ei, const int* __restrict__ rowstart,
                          int* __restrict__ cursor, int* __restrict__ csr) {
    int e = blockIdx.x * blockDim.x + threadIdx.x;
    if (e >= TE) return;
    int s, d;
    if (e < E_RAW) { s = ei[e]; d = ei[E_RAW + e]; }
    else { s = e - E_RAW; d = s; }
    int pos = atomicAdd(&cursor[d], 1);
    csr[rowstart[d] + pos] = s;
}

// ---------------- layer1 edge weights: ew1_t[h][e] = exp(lrelu(as+ad)) -------
// Also zero-fills pad slots (csr pad -> 0, weight -> 0) so gathers have no tail.
__global__ __launch_bounds__(256) void k_ew1(
    const int* __restrict__ rowstart, int* __restrict__ csr, const int* __restrict__ deg,
    const float* __restrict__ a1s, const float* __restrict__ a1d,
    float* __restrict__ ew1) {
    const int lane = threadIdx.x & 63;
    const int wid = threadIdx.x >> 6;
    const int n = blockIdx.x * 4 + wid;
    if (n >= N_NODES) return;
    const int rs = rowstart[n];
    const int dg = deg[n];
    const int re = rs + dg;
    const int re4 = rs + ((dg + 3) & ~3);
    const float4 ad = ((const float4*)a1d)[n];
    for (int i = rs + lane; i < re4; i += 64) {
        if (i < re) {
            int s = csr[i];
            float4 as = ((const float4*)a1s)[s];
            ew1[0 * TEP + i] = expf(lrelu(as.x + ad.x));
            ew1[1 * TEP + i] = expf(lrelu(as.y + ad.y));
            ew1[2 * TEP + i] = expf(lrelu(as.z + ad.z));
            ew1[3 * TEP + i] = expf(lrelu(as.w + ad.w));
        } else {
            csr[i] = 0;
            ew1[0 * TEP + i] = 0.f;
            ew1[1 * TEP + i] = 0.f;
            ew1[2 * TEP + i] = 0.f;
            ew1[3 * TEP + i] = 0.f;
        }
    }
}

// ---------------- layer1 gather: pure streaming int4/float4 + row gathers -----
__global__ __launch_bounds__(256) void k_l1_gather(
    const int* __restrict__ rowstart, const int* __restrict__ csr,
    const int* __restrict__ deg, const float* __restrict__ ew1,
    const float* __restrict__ xw1, const float* __restrict__ b1,
    float* __restrict__ h1) {
    const int lane = threadIdx.x & 63;
    const int wid = threadIdx.x >> 6;
    const int n = blockIdx.x * 4 + wid;
    if (n >= N_NODES) return;
    const int rs = rowstart[n];
    const int nb4 = (deg[n] + 3) >> 2;
    const int h = lane >> 4;
    const int4* c4 = (const int4*)(csr + rs);
    const float4* w4 = (const float4*)(ew1 + h * TEP + rs);
    const float2* xwv = (const float2*)xw1;
    float den = 0.f, ax = 0.f, ay = 0.f;
    for (int b = 0; b < nb4; ++b) {
        int4 s = c4[b];
        float4 w = w4[b];
        float2 v0 = xwv[s.x * 64 + lane], v1 = xwv[s.y * 64 + lane];
        float2 v2 = xwv[s.z * 64 + lane], v3 = xwv[s.w * 64 + lane];
        den += (w.x + w.y) + (w.z + w.w);
        ax = fmaf(w.x, v0.x, fmaf(w.y, v1.x, fmaf(w.z, v2.x, fmaf(w.w, v3.x, ax))));
        ay = fmaf(w.x, v0.y, fmaf(w.y, v1.y, fmaf(w.z, v2.y, fmaf(w.w, v3.y, ay))));
    }
    const float inv = 1.f / (den + EPS_F);
    const int c0 = 2 * lane;
    float o0 = fmaf(ax, inv, b1[c0]);
    float o1 = fmaf(ay, inv, b1[c0 + 1]);
    o0 = o0 > 0.f ? o0 : expm1f(o0);
    o1 = o1 > 0.f ? o1 : expm1f(o1);
    ((float2*)h1)[(size_t)n * 64 + lane] = make_float2(o0, o1);
}

// ---------------- layer2 matmul + attention coefs (scalar-broadcast x) -------
__global__ __launch_bounds__(64) void k_l2_mm(
    const float* __restrict__ h1, const float* __restrict__ W,
    const float* __restrict__ atts, const float* __restrict__ attd,
    float* __restrict__ xw2, float* __restrict__ a2s, float* __restrict__ a2d) {
    const int t = threadIdx.x;
    const int n0 = blockIdx.x * 16;    // 3125 blocks
    float acc[16];
#pragma unroll
    for (int j = 0; j < 16; ++j) acc[j] = 0.f;
    for (int k4 = 0; k4 < F1 / 4; ++k4) {
        int k = k4 * 4;
        float w0 = W[(k + 0) * F2 + t];
        float w1 = W[(k + 1) * F2 + t];
        float w2 = W[(k + 2) * F2 + t];
        float w3 = W[(k + 3) * F2 + t];
#pragma unroll
        for (int j = 0; j < 16; ++j) {
            float4 xv = ((const float4*)(h1 + (size_t)(n0 + j) * F1))[k4];
            acc[j] = fmaf(xv.x, w0, fmaf(xv.y, w1, fmaf(xv.z, w2, fmaf(xv.w, w3, acc[j]))));
        }
    }
    float ats = atts[t], atd = attd[t];
#pragma unroll
    for (int j = 0; j < 16; ++j) {
        int n = n0 + j;
        xw2[(size_t)n * F2 + t] = acc[j];
        float ps = acc[j] * ats, pd = acc[j] * atd;
#pragma unroll
        for (int off = 32; off; off >>= 1) {
            ps += __shfl_down(ps, off, 64);
            pd += __shfl_down(pd, off, 64);
        }
        if (t == 0) { a2s[n] = ps; a2d[n] = pd; }
    }
}

// ---------------- layer2 edge weights ----------------
__global__ __launch_bounds__(256) void k_ew2(
    const int* __restrict__ rowstart, const int* __restrict__ csr,
    const int* __restrict__ deg,
    const float* __restrict__ a2s, const float* __restrict__ a2d,
    float* __restrict__ ew2) {
    const int lane = threadIdx.x & 63;
    const int wid = threadIdx.x >> 6;
    const int n = blockIdx.x * 4 + wid;
    if (n >= N_NODES) return;
    const int rs = rowstart[n];
    const int dg = deg[n];
    const int re = rs + dg;
    const int re4 = rs + ((dg + 3) & ~3);
    const float adv = a2d[n];
    for (int i = rs + lane; i < re4; i += 64) {
        if (i < re) {
            int s = csr[i];
            ew2[i] = expf(lrelu(a2s[s] + adv));
        } else {
            ew2[i] = 0.f;
        }
    }
}

// ---------------- layer2 gather ----------------
__global__ __launch_bounds__(256) void k_l2_gather(
    const int* __restrict__ rowstart, const int* __restrict__ csr,
    const int* __restrict__ deg, const float* __restrict__ ew2,
    const float* __restrict__ xw2, float* __restrict__ h2) {
    const int lane = threadIdx.x & 63;
    const int wid = threadIdx.x >> 6;
    const int n = blockIdx.x * 4 + wid;
    if (n >= N_NODES) return;
    const int rs = rowstart[n];
    const int nb4 = (deg[n] + 3) >> 2;
    const int4* c4 = (const int4*)(csr + rs);
    const float4* w4 = (const float4*)(ew2 + rs);
    float den = 0.f, acc = 0.f;
    for (int b = 0; b < nb4; ++b) {
        int4 s = c4[b];
        float4 w = w4[b];
        float v0 = xw2[(size_t)s.x * F2 + lane], v1 = xw2[(size_t)s.y * F2 + lane];
        float v2 = xw2[(size_t)s.z * F2 + lane], v3 = xw2[(size_t)s.w * F2 + lane];
        den += (w.x + w.y) + (w.z + w.w);
        acc = fmaf(w.x, v0, fmaf(w.y, v1, fmaf(w.z, v2, fmaf(w.w, v3, acc))));
    }
    h2[(size_t)n * F2 + lane] = acc / (den + EPS_F);
}

// ---------------- mean over nodes (fp64 accum) ----------------
#define MEAN_BLOCKS 256
__global__ __launch_bounds__(256) void k_mean(const float* __restrict__ h2,
                                              double* __restrict__ accum) {
    const int t = threadIdx.x;
    const int c = t & 63;
    double acc = 0.0;
    const size_t total = (size_t)N_NODES * F2;
    for (size_t idx = (size_t)blockIdx.x * 256 + t; idx < total; idx += (size_t)MEAN_BLOCKS * 256)
        acc += (double)h2[idx];
    __shared__ double red[256];
    red[t] = acc;
    __syncthreads();
    if (t < 64) {
        double v = red[t] + red[t + 64] + red[t + 128] + red[t + 192];
        atomicAdd(&accum[c], v);
    }
}

__global__ void k_final(const double* __restrict__ accum, const float* __restrict__ b2,
                        float* __restrict__ out) {
    int t = threadIdx.x;
    if (t < F2) out[t] = (float)(accum[t] * (1.0 / (double)N_NODES)) + b2[t];
}

// ---------------- launch ----------------
extern "C" void kernel_launch(void* const* d_in, const int* in_sizes, int n_in,
                              void* d_out, int out_size, void* d_ws, size_t ws_size,
                              hipStream_t stream) {
    (void)in_sizes; (void)n_in; (void)out_size; (void)ws_size;
    const float* x   = (const float*)d_in[0];
    const int*   ei  = (const int*)d_in[1];
    const float* W1  = (const float*)d_in[2];
    const float* as1 = (const float*)d_in[3];
    const float* ad1 = (const float*)d_in[4];
    const float* b1  = (const float*)d_in[5];
    const float* W2  = (const float*)d_in[6];
    const float* as2 = (const float*)d_in[7];
    const float* ad2 = (const float*)d_in[8];
    const float* b2  = (const float*)d_in[9];
    float* out = (float*)d_out;

    char* ws = (char*)d_ws;
    size_t off = 0;
    auto alloc = [&](size_t bytes) -> void* {
        void* p = ws + off;
        off += (bytes + 255) & ~(size_t)255;
        return p;
    };
    float* xw1      = (float*)alloc((size_t)N_NODES * F1 * 4);
    float* h1       = (float*)alloc((size_t)N_NODES * F1 * 4);
    float* xw2      = (float*)alloc((size_t)N_NODES * F2 * 4);
    float* h2       = (float*)alloc((size_t)N_NODES * F2 * 4);
    float* ew1      = (float*)alloc((size_t)H1 * TEP * 4);
    float* ew2      = (float*)alloc((size_t)TEP * 4);
    float* a1s      = (float*)alloc((size_t)N_NODES * H1 * 4);
    float* a1d      = (float*)alloc((size_t)N_NODES * H1 * 4);
    float* a2s      = (float*)alloc((size_t)N_NODES * 4);
    float* a2d      = (float*)alloc((size_t)N_NODES * 4);
    int*   deg      = (int*)alloc((size_t)N_NODES * 4);
    int*   cursor   = (int*)alloc((size_t)N_NODES * 4);
    int*   rowstart = (int*)alloc((size_t)(N_NODES + 1) * 4);
    int*   csr      = (int*)alloc((size_t)TEP * 4);
    int*   incl     = (int*)alloc((size_t)N_NODES * 4);
    int*   bsum     = (int*)alloc(64 * 4);
    double* accum   = (double*)alloc(F2 * 8);

    const int nscan = (N_NODES + 1023) / 1024;  // 49
    const int nwave4 = (N_NODES + 3) / 4;       // 12500

    k_init<<<(N_NODES + 255) / 256, 256, 0, stream>>>(deg, cursor, (unsigned long long*)accum);
    k_l1_mm<<<N_NODES / 16, 128, 0, stream>>>(x, W1, as1, ad1, xw1, a1s, a1d);
    k_deg<<<(TE + 255) / 256, 256, 0, stream>>>(ei, deg);
    k_scan1<<<nscan, 1024, 0, stream>>>(deg, incl, bsum);
    k_scan2<<<1, 64, 0, stream>>>(bsum, nscan);
    k_scan3<<<nscan, 1024, 0, stream>>>(incl, bsum, rowstart);
    k_scatter<<<(TE + 255) / 256, 256, 0, stream>>>(ei, rowstart, cursor, csr);
    k_ew1<<<nwave4, 256, 0, stream>>>(rowstart, csr, deg, a1s, a1d, ew1);
    k_l1_gather<<<nwave4, 256, 0, stream>>>(rowstart, csr, deg, ew1, xw1, b1, h1);
    k_l2_mm<<<N_NODES / 16, 64, 0, stream>>>(h1, W2, as2, ad2, xw2, a2s, a2d);
    k_ew2<<<nwave4, 256, 0, stream>>>(rowstart, csr, deg, a2s, a2d, ew2);
    k_l2_gather<<<nwave4, 256, 0, stream>>>(rowstart, csr, deg, ew2, xw2, h2);
    k_mean<<<MEAN_BLOCKS, 256, 0, stream>>>(h2, accum);
    k_final<<<1, 64, 0, stream>>>(accum, b2, out);
}

// Round 4
// 608.643 us; speedup vs baseline: 1.0294x; 1.0294x over previous
//
#include <hip/hip_runtime.h>
#include <math.h>

#define N_NODES 50000
#define E_RAW   1600000
#define TE      (E_RAW + N_NODES)     // 1650000 edges incl. self loops
#define TEP     (TE + 8 * N_NODES)    // CSR padded to 8-aligned rows (upper bound)
#define F_IN    128
#define H1      4
#define F1      128                   // H1*C1
#define F2      64
#define NEG_SLOPE 0.2f
#define EPS_F   1e-16f

__device__ __forceinline__ float lrelu(float v) { return v > 0.f ? v : NEG_SLOPE * v; }

// ---------------- init: zero deg, cursor, accum ----------------
__global__ void k_init(int* __restrict__ deg, int* __restrict__ cursor,
                       unsigned long long* __restrict__ accum) {
    int i = blockIdx.x * blockDim.x + threadIdx.x;
    if (i < N_NODES) { deg[i] = 0; cursor[i] = 0; }
    if (i < F2) accum[i] = 0ULL;
}

// ---------------- layer1 matmul + attention coefs ----------------
// 16 nodes/block, 256 threads: c = t&127 (channel), p = t>>7 (node half, 8 nodes).
// x tile staged in LDS via contiguous float4 loads (rows are block-contiguous).
__global__ __launch_bounds__(256) void k_l1_mm(
    const float* __restrict__ x, const float* __restrict__ W,
    const float* __restrict__ atts, const float* __restrict__ attd,
    float* __restrict__ xw, float* __restrict__ a1s, float* __restrict__ a1d) {
    const int t = threadIdx.x;
    const int c = t & 127;
    const int p = t >> 7;
    const int n0 = blockIdx.x * 16;    // 50000 = 16*3125, no tail
    __shared__ float xs[16][F_IN];
    {   // stage 2048 contiguous floats = 512 float4
        const float4* src = (const float4*)(x + (size_t)n0 * F_IN);
        float4* dstv = (float4*)&xs[0][0];
        dstv[t] = src[t];
        dstv[t + 256] = src[t + 256];
    }
    __syncthreads();
    float acc[8];
#pragma unroll
    for (int j = 0; j < 8; ++j) acc[j] = 0.f;
    const float* xsp = &xs[p * 8][0];
    for (int k4 = 0; k4 < F_IN / 4; ++k4) {
        int k = k4 * 4;
        float w0 = W[(k + 0) * F1 + c];
        float w1 = W[(k + 1) * F1 + c];
        float w2 = W[(k + 2) * F1 + c];
        float w3 = W[(k + 3) * F1 + c];
#pragma unroll
        for (int j = 0; j < 8; ++j) {
            float4 xv = ((const float4*)(xsp + j * F_IN))[k4];
            acc[j] = fmaf(xv.x, w0, fmaf(xv.y, w1, fmaf(xv.z, w2, fmaf(xv.w, w3, acc[j]))));
        }
    }
    float ats = atts[c], atd = attd[c];
#pragma unroll
    for (int j = 0; j < 8; ++j) {
        int n = n0 + p * 8 + j;
        xw[(size_t)n * F1 + c] = acc[j];
        float ps = acc[j] * ats, pd = acc[j] * atd;
#pragma unroll
        for (int off = 16; off; off >>= 1) {
            ps += __shfl_down(ps, off, 32);
            pd += __shfl_down(pd, off, 32);
        }
        if ((t & 31) == 0) {
            int h = (c >> 5);
            a1s[n * H1 + h] = ps;
            a1d[n * H1 + h] = pd;
        }
    }
}

// ---------------- degree count ----------------
__global__ void k_deg(const int* __restrict__ ei, int* __restrict__ deg) {
    int e = blockIdx.x * blockDim.x + threadIdx.x;
    if (e >= TE) return;
    int d = (e < E_RAW) ? ei[E_RAW + e] : (e - E_RAW);
    atomicAdd(&deg[d], 1);
}

// ---------------- exclusive scan over 8-PADDED degrees (2-level) --------------
__global__ __launch_bounds__(1024) void k_scan1(const int* __restrict__ deg,
                                                int* __restrict__ incl, int* __restrict__ bsum) {
    int t = threadIdx.x, g = blockIdx.x;
    int idx = g * 1024 + t;
    int v = (idx < N_NODES) ? ((deg[idx] + 7) & ~7) : 0;
    int lane = t & 63, w = t >> 6;
#pragma unroll
    for (int off = 1; off < 64; off <<= 1) {
        int u = __shfl_up(v, off, 64);
        if (lane >= off) v += u;
    }
    __shared__ int ws[16];
    if (lane == 63) ws[w] = v;
    __syncthreads();
    if (w == 0 && lane < 16) {
        int s = ws[lane];
#pragma unroll
        for (int off = 1; off < 16; off <<= 1) {
            int u = __shfl_up(s, off, 16);
            if (lane >= off) s += u;
        }
        ws[lane] = s;
    }
    __syncthreads();
    if (w > 0) v += ws[w - 1];
    if (idx < N_NODES) incl[idx] = v;
    if (t == 1023) bsum[g] = v;
}

__global__ void k_scan2(int* __restrict__ bsum, int nblk) {
    int t = threadIdx.x;
    int v = (t < nblk) ? bsum[t] : 0;
#pragma unroll
    for (int off = 1; off < 64; off <<= 1) {
        int u = __shfl_up(v, off, 64);
        if (t >= off) v += u;
    }
    if (t < nblk) bsum[t] = v;
}

__global__ __launch_bounds__(1024) void k_scan3(const int* __restrict__ incl,
                                                const int* __restrict__ bsum,
                                                int* __restrict__ rowstart) {
    int idx = blockIdx.x * 1024 + threadIdx.x;
    if (idx >= N_NODES) return;
    int off = (blockIdx.x > 0) ? bsum[blockIdx.x - 1] : 0;
    rowstart[idx + 1] = incl[idx] + off;
    if (idx == 0) rowstart[0] = 0;
}

// ---------------- scatter into padded CSR ----------------
__global__ void k_scatter(const int* __restrict__ ei, const int* __restrict__ rowstart,
                          int* __restrict__ cursor, int* __restrict__ csr) {
    int e = blockIdx.x * blockDim.x + threadIdx.x;
    if (e >= TE) return;
    int s, d;
    if (e < E_RAW) { s = ei[e]; d = ei[E_RAW + e]; }
    else { s = e - E_RAW; d = s; }
    int pos = atomicAdd(&cursor[d], 1);
    csr[rowstart[d] + pos] = s;
}

// ---------------- layer1 edge weights + pad zero-fill ----------------
__global__ __launch_bounds__(256) void k_ew1(
    const int* __restrict__ rowstart, int* __restrict__ csr, const int* __restrict__ deg,
    const float* __restrict__ a1s, const float* __restrict__ a1d,
    float* __restrict__ ew1) {
    const int lane = threadIdx.x & 63;
    const int wid = threadIdx.x >> 6;
    const int n = blockIdx.x * 4 + wid;
    if (n >= N_NODES) return;
    const int rs = rowstart[n];
    const int dg = deg[n];
    const int re = rs + dg;
    const int re8 = rs + ((dg + 7) & ~7);
    const float4 ad = ((const float4*)a1d)[n];
    for (int i = rs + lane; i < re8; i += 64) {
        if (i < re) {
            int s = csr[i];
            float4 as = ((const float4*)a1s)[s];
            ew1[0 * TEP + i] = expf(lrelu(as.x + ad.x));
            ew1[1 * TEP + i] = expf(lrelu(as.y + ad.y));
            ew1[2 * TEP + i] = expf(lrelu(as.z + ad.z));
            ew1[3 * TEP + i] = expf(lrelu(as.w + ad.w));
        } else {
            csr[i] = 0;
            ew1[0 * TEP + i] = 0.f;
            ew1[1 * TEP + i] = 0.f;
            ew1[2 * TEP + i] = 0.f;
            ew1[3 * TEP + i] = 0.f;
        }
    }
}

// ---------------- layer1 gather: 8 edges/iter, 8 gathers in flight ------------
__global__ __launch_bounds__(256) void k_l1_gather(
    const int* __restrict__ rowstart, const int* __restrict__ csr,
    const int* __restrict__ deg, const float* __restrict__ ew1,
    const float* __restrict__ xw1, const float* __restrict__ b1,
    float* __restrict__ h1) {
    const int lane = threadIdx.x & 63;
    const int wid = threadIdx.x >> 6;
    const int n = blockIdx.x * 4 + wid;
    if (n >= N_NODES) return;
    const int rs = rowstart[n];
    const int nb8 = (deg[n] + 7) >> 3;
    const int h = lane >> 4;
    const int4* c4 = (const int4*)(csr + rs);
    const float4* w4 = (const float4*)(ew1 + h * TEP + rs);
    const float2* xwv = (const float2*)xw1;
    float den = 0.f, ax = 0.f, ay = 0.f;
    for (int b = 0; b < nb8; ++b) {
        int4 sA = c4[2 * b], sB = c4[2 * b + 1];
        float4 wA = w4[2 * b], wB = w4[2 * b + 1];
        float2 v0 = xwv[sA.x * 64 + lane], v1 = xwv[sA.y * 64 + lane];
        float2 v2 = xwv[sA.z * 64 + lane], v3 = xwv[sA.w * 64 + lane];
        float2 v4 = xwv[sB.x * 64 + lane], v5 = xwv[sB.y * 64 + lane];
        float2 v6 = xwv[sB.z * 64 + lane], v7 = xwv[sB.w * 64 + lane];
        den += ((wA.x + wA.y) + (wA.z + wA.w)) + ((wB.x + wB.y) + (wB.z + wB.w));
        ax = fmaf(wA.x, v0.x, fmaf(wA.y, v1.x, fmaf(wA.z, v2.x, fmaf(wA.w, v3.x, ax))));
        ay = fmaf(wA.x, v0.y, fmaf(wA.y, v1.y, fmaf(wA.z, v2.y, fmaf(wA.w, v3.y, ay))));
        ax = fmaf(wB.x, v4.x, fmaf(wB.y, v5.x, fmaf(wB.z, v6.x, fmaf(wB.w, v7.x, ax))));
        ay = fmaf(wB.x, v4.y, fmaf(wB.y, v5.y, fmaf(wB.z, v6.y, fmaf(wB.w, v7.y, ay))));
    }
    const float inv = 1.f / (den + EPS_F);
    const int c0 = 2 * lane;
    float o0 = fmaf(ax, inv, b1[c0]);
    float o1 = fmaf(ay, inv, b1[c0 + 1]);
    o0 = o0 > 0.f ? o0 : expm1f(o0);
    o1 = o1 > 0.f ? o1 : expm1f(o1);
    ((float2*)h1)[(size_t)n * 64 + lane] = make_float2(o0, o1);
}

// ---------------- layer2 matmul + attention coefs ----------------
// 16 nodes/block, 256 threads: c = t&63, p = t>>6 (4 nodes each).
__global__ __launch_bounds__(256) void k_l2_mm(
    const float* __restrict__ h1, const float* __restrict__ W,
    const float* __restrict__ atts, const float* __restrict__ attd,
    float* __restrict__ xw2, float* __restrict__ a2s, float* __restrict__ a2d) {
    const int t = threadIdx.x;
    const int c = t & 63;
    const int p = t >> 6;
    const int n0 = blockIdx.x * 16;    // 3125 blocks
    __shared__ float xs[16][F1];
    {
        const float4* src = (const float4*)(h1 + (size_t)n0 * F1);
        float4* dstv = (float4*)&xs[0][0];
        dstv[t] = src[t];
        dstv[t + 256] = src[t + 256];
    }
    __syncthreads();
    float acc[4];
#pragma unroll
    for (int j = 0; j < 4; ++j) acc[j] = 0.f;
    const float* xsp = &xs[p * 4][0];
    for (int k4 = 0; k4 < F1 / 4; ++k4) {
        int k = k4 * 4;
        float w0 = W[(k + 0) * F2 + c];
        float w1 = W[(k + 1) * F2 + c];
        float w2 = W[(k + 2) * F2 + c];
        float w3 = W[(k + 3) * F2 + c];
#pragma unroll
        for (int j = 0; j < 4; ++j) {
            float4 xv = ((const float4*)(xsp + j * F1))[k4];
            acc[j] = fmaf(xv.x, w0, fmaf(xv.y, w1, fmaf(xv.z, w2, fmaf(xv.w, w3, acc[j]))));
        }
    }
    float ats = atts[c], atd = attd[c];
#pragma unroll
    for (int j = 0; j < 4; ++j) {
        int n = n0 + p * 4 + j;
        xw2[(size_t)n * F2 + c] = acc[j];
        float ps = acc[j] * ats, pd = acc[j] * atd;
#pragma unroll
        for (int off = 32; off; off >>= 1) {
            ps += __shfl_down(ps, off, 64);
            pd += __shfl_down(pd, off, 64);
        }
        if (c == 0) { a2s[n] = ps; a2d[n] = pd; }
    }
}

// ---------------- layer2 edge weights ----------------
__global__ __launch_bounds__(256) void k_ew2(
    const int* __restrict__ rowstart, const int* __restrict__ csr,
    const int* __restrict__ deg,
    const float* __restrict__ a2s, const float* __restrict__ a2d,
    float* __restrict__ ew2) {
    const int lane = threadIdx.x & 63;
    const int wid = threadIdx.x >> 6;
    const int n = blockIdx.x * 4 + wid;
    if (n >= N_NODES) return;
    const int rs = rowstart[n];
    const int dg = deg[n];
    const int re = rs + dg;
    const int re8 = rs + ((dg + 7) & ~7);
    const float adv = a2d[n];
    for (int i = rs + lane; i < re8; i += 64) {
        if (i < re) {
            int s = csr[i];
            ew2[i] = expf(lrelu(a2s[s] + adv));
        } else {
            ew2[i] = 0.f;
        }
    }
}

// ---------------- layer2 gather: 8 edges/iter ----------------
__global__ __launch_bounds__(256) void k_l2_gather(
    const int* __restrict__ rowstart, const int* __restrict__ csr,
    const int* __restrict__ deg, const float* __restrict__ ew2,
    const float* __restrict__ xw2, float* __restrict__ h2) {
    const int lane = threadIdx.x & 63;
    const int wid = threadIdx.x >> 6;
    const int n = blockIdx.x * 4 + wid;
    if (n >= N_NODES) return;
    const int rs = rowstart[n];
    const int nb8 = (deg[n] + 7) >> 3;
    const int4* c4 = (const int4*)(csr + rs);
    const float4* w4 = (const float4*)(ew2 + rs);
    float den = 0.f, acc = 0.f;
    for (int b = 0; b < nb8; ++b) {
        int4 sA = c4[2 * b], sB = c4[2 * b + 1];
        float4 wA = w4[2 * b], wB = w4[2 * b + 1];
        float v0 = xw2[(size_t)sA.x * F2 + lane], v1 = xw2[(size_t)sA.y * F2 + lane];
        float v2 = xw2[(size_t)sA.z * F2 + lane], v3 = xw2[(size_t)sA.w * F2 + lane];
        float v4 = xw2[(size_t)sB.x * F2 + lane], v5 = xw2[(size_t)sB.y * F2 + lane];
        float v6 = xw2[(size_t)sB.z * F2 + lane], v7 = xw2[(size_t)sB.w * F2 + lane];
        den += ((wA.x + wA.y) + (wA.z + wA.w)) + ((wB.x + wB.y) + (wB.z + wB.w));
        acc = fmaf(wA.x, v0, fmaf(wA.y, v1, fmaf(wA.z, v2, fmaf(wA.w, v3, acc))));
        acc = fmaf(wB.x, v4, fmaf(wB.y, v5, fmaf(wB.z, v6, fmaf(wB.w, v7, acc))));
    }
    h2[(size_t)n * F2 + lane] = acc / (den + EPS_F);
}

// ---------------- mean over nodes (fp64 accum) ----------------
#define MEAN_BLOCKS 256
__global__ __launch_bounds__(256) void k_mean(const float* __restrict__ h2,
                                              double* __restrict__ accum) {
    const int t = threadIdx.x;
    const int c = t & 63;
    double acc = 0.0;
    const size_t total = (size_t)N_NODES * F2;
    for (size_t idx = (size_t)blockIdx.x * 256 + t; idx < total; idx += (size_t)MEAN_BLOCKS * 256)
        acc += (double)h2[idx];
    __shared__ double red[256];
    red[t] = acc;
    __syncthreads();
    if (t < 64) {
        double v = red[t] + red[t + 64] + red[t + 128] + red[t + 192];
        atomicAdd(&accum[c], v);
    }
}

__global__ void k_final(const double* __restrict__ accum, const float* __restrict__ b2,
                        float* __restrict__ out) {
    int t = threadIdx.x;
    if (t < F2) out[t] = (float)(accum[t] * (1.0 / (double)N_NODES)) + b2[t];
}

// ---------------- launch ----------------
extern "C" void kernel_launch(void* const* d_in, const int* in_sizes, int n_in,
                              void* d_out, int out_size, void* d_ws, size_t ws_size,
                              hipStream_t stream) {
    (void)in_sizes; (void)n_in; (void)out_size; (void)ws_size;
    const float* x   = (const float*)d_in[0];
    const int*   ei  = (const int*)d_in[1];
    const float* W1  = (const float*)d_in[2];
    const float* as1 = (const float*)d_in[3];
    const float* ad1 = (const float*)d_in[4];
    const float* b1  = (const float*)d_in[5];
    const float* W2  = (const float*)d_in[6];
    const float* as2 = (const float*)d_in[7];
    const float* ad2 = (const float*)d_in[8];
    const float* b2  = (const float*)d_in[9];
    float* out = (float*)d_out;

    char* ws = (char*)d_ws;
    size_t off = 0;
    auto alloc = [&](size_t bytes) -> void* {
        void* p = ws + off;
        off += (bytes + 255) & ~(size_t)255;
        return p;
    };
    float* xw1      = (float*)alloc((size_t)N_NODES * F1 * 4);
    float* h1       = (float*)alloc((size_t)N_NODES * F1 * 4);
    float* xw2      = (float*)alloc((size_t)N_NODES * F2 * 4);
    float* h2       = (float*)alloc((size_t)N_NODES * F2 * 4);
    float* ew1      = (float*)alloc((size_t)H1 * TEP * 4);
    float* ew2      = (float*)alloc((size_t)TEP * 4);
    float* a1s      = (float*)alloc((size_t)N_NODES * H1 * 4);
    float* a1d      = (float*)alloc((size_t)N_NODES * H1 * 4);
    float* a2s      = (float*)alloc((size_t)N_NODES * 4);
    float* a2d      = (float*)alloc((size_t)N_NODES * 4);
    int*   deg      = (int*)alloc((size_t)N_NODES * 4);
    int*   cursor   = (int*)alloc((size_t)N_NODES * 4);
    int*   rowstart = (int*)alloc((size_t)(N_NODES + 1) * 4);
    int*   csr      = (int*)alloc((size_t)TEP * 4);
    int*   incl     = (int*)alloc((size_t)N_NODES * 4);
    int*   bsum     = (int*)alloc(64 * 4);
    double* accum   = (double*)alloc(F2 * 8);

    const int nscan = (N_NODES + 1023) / 1024;  // 49
    const int nwave4 = (N_NODES + 3) / 4;       // 12500

    k_init<<<(N_NODES + 255) / 256, 256, 0, stream>>>(deg, cursor, (unsigned long long*)accum);
    k_l1_mm<<<N_NODES / 16, 256, 0, stream>>>(x, W1, as1, ad1, xw1, a1s, a1d);
    k_deg<<<(TE + 255) / 256, 256, 0, stream>>>(ei, deg);
    k_scan1<<<nscan, 1024, 0, stream>>>(deg, incl, bsum);
    k_scan2<<<1, 64, 0, stream>>>(bsum, nscan);
    k_scan3<<<nscan, 1024, 0, stream>>>(incl, bsum, rowstart);
    k_scatter<<<(TE + 255) / 256, 256, 0, stream>>>(ei, rowstart, cursor, csr);
    k_ew1<<<nwave4, 256, 0, stream>>>(rowstart, csr, deg, a1s, a1d, ew1);
    k_l1_gather<<<nwave4, 256, 0, stream>>>(rowstart, csr, deg, ew1, xw1, b1, h1);
    k_l2_mm<<<N_NODES / 16, 256, 0, stream>>>(h1, W2, as2, ad2, xw2, a2s, a2d);
    k_ew2<<<nwave4, 256, 0, stream>>>(rowstart, csr, deg, a2s, a2d, ew2);
    k_l2_gather<<<nwave4, 256, 0, stream>>>(rowstart, csr, deg, ew2, xw2, h2);
    k_mean<<<MEAN_BLOCKS, 256, 0, stream>>>(h2, accum);
    k_final<<<1, 64, 0, stream>>>(accum, b2, out);
}

// Round 5
// 520.089 us; speedup vs baseline: 1.2046x; 1.1703x over previous
//
#include <hip/hip_runtime.h>
#include <math.h>

#define N_NODES 50000
#define E_RAW   1600000
#define TE      (E_RAW + N_NODES)     // 1650000 edges incl. self loops
#define TEP     (TE + 8 * N_NODES)    // CSR padded to 8-aligned rows (upper bound)
#define F_IN    128
#define H1      4
#define F1      128                   // H1*C1
#define F2      64
#define NEG_SLOPE 0.2f
#define EPS_F   1e-16f

__device__ __forceinline__ float lrelu(float v) { return v > 0.f ? v : NEG_SLOPE * v; }

// ---------------- init: zero deg, cursor, accum ----------------
__global__ void k_init(int* __restrict__ deg, int* __restrict__ cursor,
                       unsigned long long* __restrict__ accum) {
    int i = blockIdx.x * blockDim.x + threadIdx.x;
    if (i < N_NODES) { deg[i] = 0; cursor[i] = 0; }
    if (i < F2) accum[i] = 0ULL;
}

// ---------------- layer1 matmul + attention coefs ----------------
// 16 nodes/block, 256 threads: c = t&127 (channel), p = t>>7 (node half, 8 nodes).
// x staged in LDS (contiguous float4); LDS reads are wave-uniform broadcasts.
// #pragma unroll 2 on k-loop: full unroll hoisted 128 W loads -> 256 VGPR (round 4).
__global__ __launch_bounds__(256) void k_l1_mm(
    const float* __restrict__ x, const float* __restrict__ W,
    const float* __restrict__ atts, const float* __restrict__ attd,
    float* __restrict__ xw, float* __restrict__ a1s, float* __restrict__ a1d) {
    const int t = threadIdx.x;
    const int c = t & 127;
    const int p = t >> 7;
    const int n0 = blockIdx.x * 16;    // 50000 = 16*3125, no tail
    __shared__ float xs[16][F_IN];
    {
        const float4* src = (const float4*)(x + (size_t)n0 * F_IN);
        float4* dstv = (float4*)&xs[0][0];
        dstv[t] = src[t];
        dstv[t + 256] = src[t + 256];
    }
    __syncthreads();
    float acc[8];
#pragma unroll
    for (int j = 0; j < 8; ++j) acc[j] = 0.f;
    const float* xsp = &xs[p * 8][0];
#pragma unroll 2
    for (int k4 = 0; k4 < F_IN / 4; ++k4) {
        int k = k4 * 4;
        float w0 = W[(k + 0) * F1 + c];
        float w1 = W[(k + 1) * F1 + c];
        float w2 = W[(k + 2) * F1 + c];
        float w3 = W[(k + 3) * F1 + c];
#pragma unroll
        for (int j = 0; j < 8; ++j) {
            float4 xv = ((const float4*)(xsp + j * F_IN))[k4];
            acc[j] = fmaf(xv.x, w0, fmaf(xv.y, w1, fmaf(xv.z, w2, fmaf(xv.w, w3, acc[j]))));
        }
    }
    float ats = atts[c], atd = attd[c];
#pragma unroll
    for (int j = 0; j < 8; ++j) {
        int n = n0 + p * 8 + j;
        xw[(size_t)n * F1 + c] = acc[j];
        float ps = acc[j] * ats, pd = acc[j] * atd;
#pragma unroll
        for (int off = 16; off; off >>= 1) {
            ps += __shfl_down(ps, off, 32);
            pd += __shfl_down(pd, off, 32);
        }
        if ((t & 31) == 0) {
            int h = (c >> 5);
            a1s[n * H1 + h] = ps;
            a1d[n * H1 + h] = pd;
        }
    }
}

// ---------------- degree count ----------------
__global__ void k_deg(const int* __restrict__ ei, int* __restrict__ deg) {
    int e = blockIdx.x * blockDim.x + threadIdx.x;
    if (e >= TE) return;
    int d = (e < E_RAW) ? ei[E_RAW + e] : (e - E_RAW);
    atomicAdd(&deg[d], 1);
}

// ---------------- exclusive scan over 8-PADDED degrees (2-level) --------------
__global__ __launch_bounds__(1024) void k_scan1(const int* __restrict__ deg,
                                                int* __restrict__ incl, int* __restrict__ bsum) {
    int t = threadIdx.x, g = blockIdx.x;
    int idx = g * 1024 + t;
    int v = (idx < N_NODES) ? ((deg[idx] + 7) & ~7) : 0;
    int lane = t & 63, w = t >> 6;
#pragma unroll
    for (int off = 1; off < 64; off <<= 1) {
        int u = __shfl_up(v, off, 64);
        if (lane >= off) v += u;
    }
    __shared__ int ws[16];
    if (lane == 63) ws[w] = v;
    __syncthreads();
    if (w == 0 && lane < 16) {
        int s = ws[lane];
#pragma unroll
        for (int off = 1; off < 16; off <<= 1) {
            int u = __shfl_up(s, off, 16);
            if (lane >= off) s += u;
        }
        ws[lane] = s;
    }
    __syncthreads();
    if (w > 0) v += ws[w - 1];
    if (idx < N_NODES) incl[idx] = v;
    if (t == 1023) bsum[g] = v;
}

__global__ void k_scan2(int* __restrict__ bsum, int nblk) {
    int t = threadIdx.x;
    int v = (t < nblk) ? bsum[t] : 0;
#pragma unroll
    for (int off = 1; off < 64; off <<= 1) {
        int u = __shfl_up(v, off, 64);
        if (t >= off) v += u;
    }
    if (t < nblk) bsum[t] = v;
}

__global__ __launch_bounds__(1024) void k_scan3(const int* __restrict__ incl,
                                                const int* __restrict__ bsum,
                                                int* __restrict__ rowstart) {
    int idx = blockIdx.x * 1024 + threadIdx.x;
    if (idx >= N_NODES) return;
    int off = (blockIdx.x > 0) ? bsum[blockIdx.x - 1] : 0;
    rowstart[idx + 1] = incl[idx] + off;
    if (idx == 0) rowstart[0] = 0;
}

// ---------------- scatter into padded CSR ----------------
__global__ void k_scatter(const int* __restrict__ ei, const int* __restrict__ rowstart,
                          int* __restrict__ cursor, int* __restrict__ csr) {
    int e = blockIdx.x * blockDim.x + threadIdx.x;
    if (e >= TE) return;
    int s, d;
    if (e < E_RAW) { s = ei[e]; d = ei[E_RAW + e]; }
    else { s = e - E_RAW; d = s; }
    int pos = atomicAdd(&cursor[d], 1);
    csr[rowstart[d] + pos] = s;
}

// ---------------- layer1 edge weights + pad zero-fill ----------------
__global__ __launch_bounds__(256) void k_ew1(
    const int* __restrict__ rowstart, int* __restrict__ csr, const int* __restrict__ deg,
    const float* __restrict__ a1s, const float* __restrict__ a1d,
    float* __restrict__ ew1) {
    const int lane = threadIdx.x & 63;
    const int wid = threadIdx.x >> 6;
    const int n = blockIdx.x * 4 + wid;
    if (n >= N_NODES) return;
    const int rs = rowstart[n];
    const int dg = deg[n];
    const int re = rs + dg;
    const int re8 = rs + ((dg + 7) & ~7);
    const float4 ad = ((const float4*)a1d)[n];
    for (int i = rs + lane; i < re8; i += 64) {
        if (i < re) {
            int s = csr[i];
            float4 as = ((const float4*)a1s)[s];
            ew1[0 * TEP + i] = expf(lrelu(as.x + ad.x));
            ew1[1 * TEP + i] = expf(lrelu(as.y + ad.y));
            ew1[2 * TEP + i] = expf(lrelu(as.z + ad.z));
            ew1[3 * TEP + i] = expf(lrelu(as.w + ad.w));
        } else {
            csr[i] = 0;
            ew1[0 * TEP + i] = 0.f;
            ew1[1 * TEP + i] = 0.f;
            ew1[2 * TEP + i] = 0.f;
            ew1[3 * TEP + i] = 0.f;
        }
    }
}

// ---------------- layer1 gather: 16 edges/iter (2x8) + 8-edge tail -----------
__global__ __launch_bounds__(256) void k_l1_gather(
    const int* __restrict__ rowstart, const int* __restrict__ csr,
    const int* __restrict__ deg, const float* __restrict__ ew1,
    const float* __restrict__ xw1, const float* __restrict__ b1,
    float* __restrict__ h1) {
    const int lane = threadIdx.x & 63;
    const int wid = threadIdx.x >> 6;
    const int n = blockIdx.x * 4 + wid;
    if (n >= N_NODES) return;
    const int rs = rowstart[n];
    const int nb8 = (deg[n] + 7) >> 3;
    const int h = lane >> 4;
    const int4* c4 = (const int4*)(csr + rs);
    const float4* w4 = (const float4*)(ew1 + h * TEP + rs);
    const float2* xwv = (const float2*)xw1;
    float den = 0.f, ax = 0.f, ay = 0.f;
    int b = 0;
    for (; b + 2 <= nb8; b += 2) {
        int4 sA = c4[2 * b], sB = c4[2 * b + 1], sC = c4[2 * b + 2], sD = c4[2 * b + 3];
        float4 wA = w4[2 * b], wB = w4[2 * b + 1], wC = w4[2 * b + 2], wD = w4[2 * b + 3];
        float2 v0 = xwv[sA.x * 64 + lane], v1 = xwv[sA.y * 64 + lane];
        float2 v2 = xwv[sA.z * 64 + lane], v3 = xwv[sA.w * 64 + lane];
        float2 v4 = xwv[sB.x * 64 + lane], v5 = xwv[sB.y * 64 + lane];
        float2 v6 = xwv[sB.z * 64 + lane], v7 = xwv[sB.w * 64 + lane];
        float2 v8 = xwv[sC.x * 64 + lane], v9 = xwv[sC.y * 64 + lane];
        float2 vA = xwv[sC.z * 64 + lane], vB = xwv[sC.w * 64 + lane];
        float2 vC = xwv[sD.x * 64 + lane], vD = xwv[sD.y * 64 + lane];
        float2 vE = xwv[sD.z * 64 + lane], vF = xwv[sD.w * 64 + lane];
        den += ((wA.x + wA.y) + (wA.z + wA.w)) + ((wB.x + wB.y) + (wB.z + wB.w))
             + ((wC.x + wC.y) + (wC.z + wC.w)) + ((wD.x + wD.y) + (wD.z + wD.w));
        ax = fmaf(wA.x, v0.x, fmaf(wA.y, v1.x, fmaf(wA.z, v2.x, fmaf(wA.w, v3.x, ax))));
        ay = fmaf(wA.x, v0.y, fmaf(wA.y, v1.y, fmaf(wA.z, v2.y, fmaf(wA.w, v3.y, ay))));
        ax = fmaf(wB.x, v4.x, fmaf(wB.y, v5.x, fmaf(wB.z, v6.x, fmaf(wB.w, v7.x, ax))));
        ay = fmaf(wB.x, v4.y, fmaf(wB.y, v5.y, fmaf(wB.z, v6.y, fmaf(wB.w, v7.y, ay))));
        ax = fmaf(wC.x, v8.x, fmaf(wC.y, v9.x, fmaf(wC.z, vA.x, fmaf(wC.w, vB.x, ax))));
        ay = fmaf(wC.x, v8.y, fmaf(wC.y, v9.y, fmaf(wC.z, vA.y, fmaf(wC.w, vB.y, ay))));
        ax = fmaf(wD.x, vC.x, fmaf(wD.y, vD.x, fmaf(wD.z, vE.x, fmaf(wD.w, vF.x, ax))));
        ay = fmaf(wD.x, vC.y, fmaf(wD.y, vD.y, fmaf(wD.z, vE.y, fmaf(wD.w, vF.y, ay))));
    }
    if (b < nb8) {
        int4 sA = c4[2 * b], sB = c4[2 * b + 1];
        float4 wA = w4[2 * b], wB = w4[2 * b + 1];
        float2 v0 = xwv[sA.x * 64 + lane], v1 = xwv[sA.y * 64 + lane];
        float2 v2 = xwv[sA.z * 64 + lane], v3 = xwv[sA.w * 64 + lane];
        float2 v4 = xwv[sB.x * 64 + lane], v5 = xwv[sB.y * 64 + lane];
        float2 v6 = xwv[sB.z * 64 + lane], v7 = xwv[sB.w * 64 + lane];
        den += ((wA.x + wA.y) + (wA.z + wA.w)) + ((wB.x + wB.y) + (wB.z + wB.w));
        ax = fmaf(wA.x, v0.x, fmaf(wA.y, v1.x, fmaf(wA.z, v2.x, fmaf(wA.w, v3.x, ax))));
        ay = fmaf(wA.x, v0.y, fmaf(wA.y, v1.y, fmaf(wA.z, v2.y, fmaf(wA.w, v3.y, ay))));
        ax = fmaf(wB.x, v4.x, fmaf(wB.y, v5.x, fmaf(wB.z, v6.x, fmaf(wB.w, v7.x, ax))));
        ay = fmaf(wB.x, v4.y, fmaf(wB.y, v5.y, fmaf(wB.z, v6.y, fmaf(wB.w, v7.y, ay))));
    }
    const float inv = 1.f / (den + EPS_F);
    const int c0 = 2 * lane;
    float o0 = fmaf(ax, inv, b1[c0]);
    float o1 = fmaf(ay, inv, b1[c0 + 1]);
    o0 = o0 > 0.f ? o0 : expm1f(o0);
    o1 = o1 > 0.f ? o1 : expm1f(o1);
    ((float2*)h1)[(size_t)n * 64 + lane] = make_float2(o0, o1);
}

// ---------------- layer2 matmul + attention coefs ----------------
// 16 nodes/block, 256 threads: c = t&63, p = t>>6 (4 nodes each).
__global__ __launch_bounds__(256) void k_l2_mm(
    const float* __restrict__ h1, const float* __restrict__ W,
    const float* __restrict__ atts, const float* __restrict__ attd,
    float* __restrict__ xw2, float* __restrict__ a2s, float* __restrict__ a2d) {
    const int t = threadIdx.x;
    const int c = t & 63;
    const int p = t >> 6;
    const int n0 = blockIdx.x * 16;    // 3125 blocks
    __shared__ float xs[16][F1];
    {
        const float4* src = (const float4*)(h1 + (size_t)n0 * F1);
        float4* dstv = (float4*)&xs[0][0];
        dstv[t] = src[t];
        dstv[t + 256] = src[t + 256];
    }
    __syncthreads();
    float acc[4];
#pragma unroll
    for (int j = 0; j < 4; ++j) acc[j] = 0.f;
    const float* xsp = &xs[p * 4][0];
#pragma unroll 2
    for (int k4 = 0; k4 < F1 / 4; ++k4) {
        int k = k4 * 4;
        float w0 = W[(k + 0) * F2 + c];
        float w1 = W[(k + 1) * F2 + c];
        float w2 = W[(k + 2) * F2 + c];
        float w3 = W[(k + 3) * F2 + c];
#pragma unroll
        for (int j = 0; j < 4; ++j) {
            float4 xv = ((const float4*)(xsp + j * F1))[k4];
            acc[j] = fmaf(xv.x, w0, fmaf(xv.y, w1, fmaf(xv.z, w2, fmaf(xv.w, w3, acc[j]))));
        }
    }
    float ats = atts[c], atd = attd[c];
#pragma unroll
    for (int j = 0; j < 4; ++j) {
        int n = n0 + p * 4 + j;
        xw2[(size_t)n * F2 + c] = acc[j];
        float ps = acc[j] * ats, pd = acc[j] * atd;
#pragma unroll
        for (int off = 32; off; off >>= 1) {
            ps += __shfl_down(ps, off, 64);
            pd += __shfl_down(pd, off, 64);
        }
        if (c == 0) { a2s[n] = ps; a2d[n] = pd; }
    }
}

// ---------------- layer2 edge weights ----------------
__global__ __launch_bounds__(256) void k_ew2(
    const int* __restrict__ rowstart, const int* __restrict__ csr,
    const int* __restrict__ deg,
    const float* __restrict__ a2s, const float* __restrict__ a2d,
    float* __restrict__ ew2) {
    const int lane = threadIdx.x & 63;
    const int wid = threadIdx.x >> 6;
    const int n = blockIdx.x * 4 + wid;
    if (n >= N_NODES) return;
    const int rs = rowstart[n];
    const int dg = deg[n];
    const int re = rs + dg;
    const int re8 = rs + ((dg + 7) & ~7);
    const float adv = a2d[n];
    for (int i = rs + lane; i < re8; i += 64) {
        if (i < re) {
            int s = csr[i];
            ew2[i] = expf(lrelu(a2s[s] + adv));
        } else {
            ew2[i] = 0.f;
        }
    }
}

// ---------------- layer2 gather: 16 edges/iter + 8-edge tail ----------------
__global__ __launch_bounds__(256) void k_l2_gather(
    const int* __restrict__ rowstart, const int* __restrict__ csr,
    const int* __restrict__ deg, const float* __restrict__ ew2,
    const float* __restrict__ xw2, float* __restrict__ h2) {
    const int lane = threadIdx.x & 63;
    const int wid = threadIdx.x >> 6;
    const int n = blockIdx.x * 4 + wid;
    if (n >= N_NODES) return;
    const int rs = rowstart[n];
    const int nb8 = (deg[n] + 7) >> 3;
    const int4* c4 = (const int4*)(csr + rs);
    const float4* w4 = (const float4*)(ew2 + rs);
    float den = 0.f, acc = 0.f;
    int b = 0;
    for (; b + 2 <= nb8; b += 2) {
        int4 sA = c4[2 * b], sB = c4[2 * b + 1], sC = c4[2 * b + 2], sD = c4[2 * b + 3];
        float4 wA = w4[2 * b], wB = w4[2 * b + 1], wC = w4[2 * b + 2], wD = w4[2 * b + 3];
        float v0 = xw2[(size_t)sA.x * F2 + lane], v1 = xw2[(size_t)sA.y * F2 + lane];
        float v2 = xw2[(size_t)sA.z * F2 + lane], v3 = xw2[(size_t)sA.w * F2 + lane];
        float v4 = xw2[(size_t)sB.x * F2 + lane], v5 = xw2[(size_t)sB.y * F2 + lane];
        float v6 = xw2[(size_t)sB.z * F2 + lane], v7 = xw2[(size_t)sB.w * F2 + lane];
        float v8 = xw2[(size_t)sC.x * F2 + lane], v9 = xw2[(size_t)sC.y * F2 + lane];
        float vA = xw2[(size_t)sC.z * F2 + lane], vB = xw2[(size_t)sC.w * F2 + lane];
        float vC = xw2[(size_t)sD.x * F2 + lane], vD = xw2[(size_t)sD.y * F2 + lane];
        float vE = xw2[(size_t)sD.z * F2 + lane], vF = xw2[(size_t)sD.w * F2 + lane];
        den += ((wA.x + wA.y) + (wA.z + wA.w)) + ((wB.x + wB.y) + (wB.z + wB.w))
             + ((wC.x + wC.y) + (wC.z + wC.w)) + ((wD.x + wD.y) + (wD.z + wD.w));
        acc = fmaf(wA.x, v0, fmaf(wA.y, v1, fmaf(wA.z, v2, fmaf(wA.w, v3, acc))));
        acc = fmaf(wB.x, v4, fmaf(wB.y, v5, fmaf(wB.z, v6, fmaf(wB.w, v7, acc))));
        acc = fmaf(wC.x, v8, fmaf(wC.y, v9, fmaf(wC.z, vA, fmaf(wC.w, vB, acc))));
        acc = fmaf(wD.x, vC, fmaf(wD.y, vD, fmaf(wD.z, vE, fmaf(wD.w, vF, acc))));
    }
    if (b < nb8) {
        int4 sA = c4[2 * b], sB = c4[2 * b + 1];
        float4 wA = w4[2 * b], wB = w4[2 * b + 1];
        float v0 = xw2[(size_t)sA.x * F2 + lane], v1 = xw2[(size_t)sA.y * F2 + lane];
        float v2 = xw2[(size_t)sA.z * F2 + lane], v3 = xw2[(size_t)sA.w * F2 + lane];
        float v4 = xw2[(size_t)sB.x * F2 + lane], v5 = xw2[(size_t)sB.y * F2 + lane];
        float v6 = xw2[(size_t)sB.z * F2 + lane], v7 = xw2[(size_t)sB.w * F2 + lane];
        den += ((wA.x + wA.y) + (wA.z + wA.w)) + ((wB.x + wB.y) + (wB.z + wB.w));
        acc = fmaf(wA.x, v0, fmaf(wA.y, v1, fmaf(wA.z, v2, fmaf(wA.w, v3, acc))));
        acc = fmaf(wB.x, v4, fmaf(wB.y, v5, fmaf(wB.z, v6, fmaf(wB.w, v7, acc))));
    }
    h2[(size_t)n * F2 + lane] = acc / (den + EPS_F);
}

// ---------------- mean over nodes (fp64 accum) ----------------
#define MEAN_BLOCKS 256
__global__ __launch_bounds__(256) void k_mean(const float* __restrict__ h2,
                                              double* __restrict__ accum) {
    const int t = threadIdx.x;
    const int c = t & 63;
    double acc = 0.0;
    const size_t total = (size_t)N_NODES * F2;
    for (size_t idx = (size_t)blockIdx.x * 256 + t; idx < total; idx += (size_t)MEAN_BLOCKS * 256)
        acc += (double)h2[idx];
    __shared__ double red[256];
    red[t] = acc;
    __syncthreads();
    if (t < 64) {
        double v = red[t] + red[t + 64] + red[t + 128] + red[t + 192];
        atomicAdd(&accum[c], v);
    }
}

__global__ void k_final(const double* __restrict__ accum, const float* __restrict__ b2,
                        float* __restrict__ out) {
    int t = threadIdx.x;
    if (t < F2) out[t] = (float)(accum[t] * (1.0 / (double)N_NODES)) + b2[t];
}

// ---------------- launch ----------------
extern "C" void kernel_launch(void* const* d_in, const int* in_sizes, int n_in,
                              void* d_out, int out_size, void* d_ws, size_t ws_size,
                              hipStream_t stream) {
    (void)in_sizes; (void)n_in; (void)out_size; (void)ws_size;
    const float* x   = (const float*)d_in[0];
    const int*   ei  = (const int*)d_in[1];
    const float* W1  = (const float*)d_in[2];
    const float* as1 = (const float*)d_in[3];
    const float* ad1 = (const float*)d_in[4];
    const float* b1  = (const float*)d_in[5];
    const float* W2  = (const float*)d_in[6];
    const float* as2 = (const float*)d_in[7];
    const float* ad2 = (const float*)d_in[8];
    const float* b2  = (const float*)d_in[9];
    float* out = (float*)d_out;

    char* ws = (char*)d_ws;
    size_t off = 0;
    auto alloc = [&](size_t bytes) -> void* {
        void* p = ws + off;
        off += (bytes + 255) & ~(size_t)255;
        return p;
    };
    float* xw1      = (float*)alloc((size_t)N_NODES * F1 * 4);
    float* h1       = (float*)alloc((size_t)N_NODES * F1 * 4);
    float* xw2      = (float*)alloc((size_t)N_NODES * F2 * 4);
    float* h2       = (float*)alloc((size_t)N_NODES * F2 * 4);
    float* ew1      = (float*)alloc((size_t)H1 * TEP * 4);
    float* ew2      = (float*)alloc((size_t)TEP * 4);
    float* a1s      = (float*)alloc((size_t)N_NODES * H1 * 4);
    float* a1d      = (float*)alloc((size_t)N_NODES * H1 * 4);
    float* a2s      = (float*)alloc((size_t)N_NODES * 4);
    float* a2d      = (float*)alloc((size_t)N_NODES * 4);
    int*   deg      = (int*)alloc((size_t)N_NODES * 4);
    int*   cursor   = (int*)alloc((size_t)N_NODES * 4);
    int*   rowstart = (int*)alloc((size_t)(N_NODES + 1) * 4);
    int*   csr      = (int*)alloc((size_t)TEP * 4);
    int*   incl     = (int*)alloc((size_t)N_NODES * 4);
    int*   bsum     = (int*)alloc(64 * 4);
    double* accum   = (double*)alloc(F2 * 8);

    const int nscan = (N_NODES + 1023) / 1024;  // 49
    const int nwave4 = (N_NODES + 3) / 4;       // 12500

    k_init<<<(N_NODES + 255) / 256, 256, 0, stream>>>(deg, cursor, (unsigned long long*)accum);
    k_l1_mm<<<N_NODES / 16, 256, 0, stream>>>(x, W1, as1, ad1, xw1, a1s, a1d);
    k_deg<<<(TE + 255) / 256, 256, 0, stream>>>(ei, deg);
    k_scan1<<<nscan, 1024, 0, stream>>>(deg, incl, bsum);
    k_scan2<<<1, 64, 0, stream>>>(bsum, nscan);
    k_scan3<<<nscan, 1024, 0, stream>>>(incl, bsum, rowstart);
    k_scatter<<<(TE + 255) / 256, 256, 0, stream>>>(ei, rowstart, cursor, csr);
    k_ew1<<<nwave4, 256, 0, stream>>>(rowstart, csr, deg, a1s, a1d, ew1);
    k_l1_gather<<<nwave4, 256, 0, stream>>>(rowstart, csr, deg, ew1, xw1, b1, h1);
    k_l2_mm<<<N_NODES / 16, 256, 0, stream>>>(h1, W2, as2, ad2, xw2, a2s, a2d);
    k_ew2<<<nwave4, 256, 0, stream>>>(rowstart, csr, deg, a2s, a2d, ew2);
    k_l2_gather<<<nwave4, 256, 0, stream>>>(rowstart, csr, deg, ew2, xw2, h2);
    k_mean<<<MEAN_BLOCKS, 256, 0, stream>>>(h2, accum);
    k_final<<<1, 64, 0, stream>>>(accum, b2, out);
}

// Round 6
// 470.980 us; speedup vs baseline: 1.3302x; 1.1043x over previous
//
#include <hip/hip_runtime.h>
#include <math.h>

#define N_NODES 50000
#define E_RAW   1600000
#define TE      (E_RAW + N_NODES)     // 1650000 edges incl. self loops
#define TEP     (TE + 8 * N_NODES)    // CSR padded to 8-aligned rows (upper bound)
#define F_IN    128
#define H1      4
#define F1      128                   // H1*C1
#define F2      64
#define NEG_SLOPE 0.2f
#define EPS_F   1e-16f

__device__ __forceinline__ float lrelu(float v) { return v > 0.f ? v : NEG_SLOPE * v; }

// bf16 round-to-nearest-even pack/unpack (values here are tame: no NaN/Inf)
__device__ __forceinline__ unsigned short f2bf(float f) {
    unsigned u = __float_as_uint(f);
    return (unsigned short)((u + 0x7fffu + ((u >> 16) & 1u)) >> 16);
}
__device__ __forceinline__ float2 bfpair2f(unsigned u) {
    float2 r;
    r.x = __uint_as_float(u << 16);          // low ushort  = even channel
    r.y = __uint_as_float(u & 0xffff0000u);  // high ushort = odd channel
    return r;
}
__device__ __forceinline__ float bf2f(unsigned short s) {
    return __uint_as_float(((unsigned)s) << 16);
}

// ---------------- init: zero deg, cursor, accum ----------------
__global__ void k_init(int* __restrict__ deg, int* __restrict__ cursor,
                       unsigned long long* __restrict__ accum) {
    int i = blockIdx.x * blockDim.x + threadIdx.x;
    if (i < N_NODES) { deg[i] = 0; cursor[i] = 0; }
    if (i < F2) accum[i] = 0ULL;
}

// ---------------- layer1 matmul + attention coefs ----------------
// 16 nodes/block, 256 threads: c = t&127 (channel), p = t>>7 (node half, 8 nodes).
// xw stored bf16 (gather table); attention coefs fp32-exact from registers.
// #pragma unroll 2: full unroll -> 256 VGPR cliff (round 4).
__global__ __launch_bounds__(256) void k_l1_mm(
    const float* __restrict__ x, const float* __restrict__ W,
    const float* __restrict__ atts, const float* __restrict__ attd,
    unsigned short* __restrict__ xwbf, float* __restrict__ a1s, float* __restrict__ a1d) {
    const int t = threadIdx.x;
    const int c = t & 127;
    const int p = t >> 7;
    const int n0 = blockIdx.x * 16;    // 50000 = 16*3125, no tail
    __shared__ float xs[16][F_IN];
    {
        const float4* src = (const float4*)(x + (size_t)n0 * F_IN);
        float4* dstv = (float4*)&xs[0][0];
        dstv[t] = src[t];
        dstv[t + 256] = src[t + 256];
    }
    __syncthreads();
    float acc[8];
#pragma unroll
    for (int j = 0; j < 8; ++j) acc[j] = 0.f;
    const float* xsp = &xs[p * 8][0];
#pragma unroll 2
    for (int k4 = 0; k4 < F_IN / 4; ++k4) {
        int k = k4 * 4;
        float w0 = W[(k + 0) * F1 + c];
        float w1 = W[(k + 1) * F1 + c];
        float w2 = W[(k + 2) * F1 + c];
        float w3 = W[(k + 3) * F1 + c];
#pragma unroll
        for (int j = 0; j < 8; ++j) {
            float4 xv = ((const float4*)(xsp + j * F_IN))[k4];
            acc[j] = fmaf(xv.x, w0, fmaf(xv.y, w1, fmaf(xv.z, w2, fmaf(xv.w, w3, acc[j]))));
        }
    }
    float ats = atts[c], atd = attd[c];
#pragma unroll
    for (int j = 0; j < 8; ++j) {
        int n = n0 + p * 8 + j;
        xwbf[(size_t)n * F1 + c] = f2bf(acc[j]);
        float ps = acc[j] * ats, pd = acc[j] * atd;
#pragma unroll
        for (int off = 16; off; off >>= 1) {
            ps += __shfl_down(ps, off, 32);
            pd += __shfl_down(pd, off, 32);
        }
        if ((t & 31) == 0) {
            int h = (c >> 5);
            a1s[n * H1 + h] = ps;
            a1d[n * H1 + h] = pd;
        }
    }
}

// ---------------- degree count ----------------
__global__ void k_deg(const int* __restrict__ ei, int* __restrict__ deg) {
    int e = blockIdx.x * blockDim.x + threadIdx.x;
    if (e >= TE) return;
    int d = (e < E_RAW) ? ei[E_RAW + e] : (e - E_RAW);
    atomicAdd(&deg[d], 1);
}

// ---------------- exclusive scan over 8-PADDED degrees (2-level) --------------
__global__ __launch_bounds__(1024) void k_scan1(const int* __restrict__ deg,
                                                int* __restrict__ incl, int* __restrict__ bsum) {
    int t = threadIdx.x, g = blockIdx.x;
    int idx = g * 1024 + t;
    int v = (idx < N_NODES) ? ((deg[idx] + 7) & ~7) : 0;
    int lane = t & 63, w = t >> 6;
#pragma unroll
    for (int off = 1; off < 64; off <<= 1) {
        int u = __shfl_up(v, off, 64);
        if (lane >= off) v += u;
    }
    __shared__ int ws[16];
    if (lane == 63) ws[w] = v;
    __syncthreads();
    if (w == 0 && lane < 16) {
        int s = ws[lane];
#pragma unroll
        for (int off = 1; off < 16; off <<= 1) {
            int u = __shfl_up(s, off, 16);
            if (lane >= off) s += u;
        }
        ws[lane] = s;
    }
    __syncthreads();
    if (w > 0) v += ws[w - 1];
    if (idx < N_NODES) incl[idx] = v;
    if (t == 1023) bsum[g] = v;
}

__global__ void k_scan2(int* __restrict__ bsum, int nblk) {
    int t = threadIdx.x;
    int v = (t < nblk) ? bsum[t] : 0;
#pragma unroll
    for (int off = 1; off < 64; off <<= 1) {
        int u = __shfl_up(v, off, 64);
        if (t >= off) v += u;
    }
    if (t < nblk) bsum[t] = v;
}

__global__ __launch_bounds__(1024) void k_scan3(const int* __restrict__ incl,
                                                const int* __restrict__ bsum,
                                                int* __restrict__ rowstart) {
    int idx = blockIdx.x * 1024 + threadIdx.x;
    if (idx >= N_NODES) return;
    int off = (blockIdx.x > 0) ? bsum[blockIdx.x - 1] : 0;
    rowstart[idx + 1] = incl[idx] + off;
    if (idx == 0) rowstart[0] = 0;
}

// ---------------- scatter into padded CSR ----------------
__global__ void k_scatter(const int* __restrict__ ei, const int* __restrict__ rowstart,
                          int* __restrict__ cursor, int* __restrict__ csr) {
    int e = blockIdx.x * blockDim.x + threadIdx.x;
    if (e >= TE) return;
    int s, d;
    if (e < E_RAW) { s = ei[e]; d = ei[E_RAW + e]; }
    else { s = e - E_RAW; d = s; }
    int pos = atomicAdd(&cursor[d], 1);
    csr[rowstart[d] + pos] = s;
}

// ---------------- layer1 edge weights + pad zero-fill ----------------
__global__ __launch_bounds__(256) void k_ew1(
    const int* __restrict__ rowstart, int* __restrict__ csr, const int* __restrict__ deg,
    const float* __restrict__ a1s, const float* __restrict__ a1d,
    float* __restrict__ ew1) {
    const int lane = threadIdx.x & 63;
    const int wid = threadIdx.x >> 6;
    const int n = blockIdx.x * 4 + wid;
    if (n >= N_NODES) return;
    const int rs = rowstart[n];
    const int dg = deg[n];
    const int re = rs + dg;
    const int re8 = rs + ((dg + 7) & ~7);
    const float4 ad = ((const float4*)a1d)[n];
    for (int i = rs + lane; i < re8; i += 64) {
        if (i < re) {
            int s = csr[i];
            float4 as = ((const float4*)a1s)[s];
            ew1[0 * TEP + i] = expf(lrelu(as.x + ad.x));
            ew1[1 * TEP + i] = expf(lrelu(as.y + ad.y));
            ew1[2 * TEP + i] = expf(lrelu(as.z + ad.z));
            ew1[3 * TEP + i] = expf(lrelu(as.w + ad.w));
        } else {
            csr[i] = 0;
            ew1[0 * TEP + i] = 0.f;
            ew1[1 * TEP + i] = 0.f;
            ew1[2 * TEP + i] = 0.f;
            ew1[3 * TEP + i] = 0.f;
        }
    }
}

// ---------------- layer1 gather: bf16 rows, 8 edges/iter ----------------
__global__ __launch_bounds__(256) void k_l1_gather(
    const int* __restrict__ rowstart, const int* __restrict__ csr,
    const int* __restrict__ deg, const float* __restrict__ ew1,
    const unsigned short* __restrict__ xwbf, const float* __restrict__ b1,
    float* __restrict__ h1) {
    const int lane = threadIdx.x & 63;
    const int wid = threadIdx.x >> 6;
    const int n = blockIdx.x * 4 + wid;
    if (n >= N_NODES) return;
    const int rs = rowstart[n];
    const int nb8 = (deg[n] + 7) >> 3;
    const int h = lane >> 4;
    const int4* c4 = (const int4*)(csr + rs);
    const float4* w4 = (const float4*)(ew1 + h * TEP + rs);
    const unsigned* xwv = (const unsigned*)xwbf;   // 1 uint = 2 bf16 channels
    float den = 0.f, ax = 0.f, ay = 0.f;
    for (int b = 0; b < nb8; ++b) {
        int4 sA = c4[2 * b], sB = c4[2 * b + 1];
        float4 wA = w4[2 * b], wB = w4[2 * b + 1];
        unsigned u0 = xwv[sA.x * 64 + lane], u1 = xwv[sA.y * 64 + lane];
        unsigned u2 = xwv[sA.z * 64 + lane], u3 = xwv[sA.w * 64 + lane];
        unsigned u4 = xwv[sB.x * 64 + lane], u5 = xwv[sB.y * 64 + lane];
        unsigned u6 = xwv[sB.z * 64 + lane], u7 = xwv[sB.w * 64 + lane];
        float2 v0 = bfpair2f(u0), v1 = bfpair2f(u1), v2 = bfpair2f(u2), v3 = bfpair2f(u3);
        float2 v4 = bfpair2f(u4), v5 = bfpair2f(u5), v6 = bfpair2f(u6), v7 = bfpair2f(u7);
        den += ((wA.x + wA.y) + (wA.z + wA.w)) + ((wB.x + wB.y) + (wB.z + wB.w));
        ax = fmaf(wA.x, v0.x, fmaf(wA.y, v1.x, fmaf(wA.z, v2.x, fmaf(wA.w, v3.x, ax))));
        ay = fmaf(wA.x, v0.y, fmaf(wA.y, v1.y, fmaf(wA.z, v2.y, fmaf(wA.w, v3.y, ay))));
        ax = fmaf(wB.x, v4.x, fmaf(wB.y, v5.x, fmaf(wB.z, v6.x, fmaf(wB.w, v7.x, ax))));
        ay = fmaf(wB.x, v4.y, fmaf(wB.y, v5.y, fmaf(wB.z, v6.y, fmaf(wB.w, v7.y, ay))));
    }
    const float inv = 1.f / (den + EPS_F);
    const int c0 = 2 * lane;
    float o0 = fmaf(ax, inv, b1[c0]);
    float o1 = fmaf(ay, inv, b1[c0 + 1]);
    o0 = o0 > 0.f ? o0 : expm1f(o0);
    o1 = o1 > 0.f ? o1 : expm1f(o1);
    ((float2*)h1)[(size_t)n * 64 + lane] = make_float2(o0, o1);
}

// ---------------- layer2 matmul + attention coefs ----------------
// 16 nodes/block, 256 threads: c = t&63, p = t>>6 (4 nodes each). xw2 bf16.
__global__ __launch_bounds__(256) void k_l2_mm(
    const float* __restrict__ h1, const float* __restrict__ W,
    const float* __restrict__ atts, const float* __restrict__ attd,
    unsigned short* __restrict__ xwbf, float* __restrict__ a2s, float* __restrict__ a2d) {
    const int t = threadIdx.x;
    const int c = t & 63;
    const int p = t >> 6;
    const int n0 = blockIdx.x * 16;    // 3125 blocks
    __shared__ float xs[16][F1];
    {
        const float4* src = (const float4*)(h1 + (size_t)n0 * F1);
        float4* dstv = (float4*)&xs[0][0];
        dstv[t] = src[t];
        dstv[t + 256] = src[t + 256];
    }
    __syncthreads();
    float acc[4];
#pragma unroll
    for (int j = 0; j < 4; ++j) acc[j] = 0.f;
    const float* xsp = &xs[p * 4][0];
#pragma unroll 2
    for (int k4 = 0; k4 < F1 / 4; ++k4) {
        int k = k4 * 4;
        float w0 = W[(k + 0) * F2 + c];
        float w1 = W[(k + 1) * F2 + c];
        float w2 = W[(k + 2) * F2 + c];
        float w3 = W[(k + 3) * F2 + c];
#pragma unroll
        for (int j = 0; j < 4; ++j) {
            float4 xv = ((const float4*)(xsp + j * F1))[k4];
            acc[j] = fmaf(xv.x, w0, fmaf(xv.y, w1, fmaf(xv.z, w2, fmaf(xv.w, w3, acc[j]))));
        }
    }
    float ats = atts[c], atd = attd[c];
#pragma unroll
    for (int j = 0; j < 4; ++j) {
        int n = n0 + p * 4 + j;
        xwbf[(size_t)n * F2 + c] = f2bf(acc[j]);
        float ps = acc[j] * ats, pd = acc[j] * atd;
#pragma unroll
        for (int off = 32; off; off >>= 1) {
            ps += __shfl_down(ps, off, 64);
            pd += __shfl_down(pd, off, 64);
        }
        if (c == 0) { a2s[n] = ps; a2d[n] = pd; }
    }
}

// ---------------- layer2 edge weights ----------------
__global__ __launch_bounds__(256) void k_ew2(
    const int* __restrict__ rowstart, const int* __restrict__ csr,
    const int* __restrict__ deg,
    const float* __restrict__ a2s, const float* __restrict__ a2d,
    float* __restrict__ ew2) {
    const int lane = threadIdx.x & 63;
    const int wid = threadIdx.x >> 6;
    const int n = blockIdx.x * 4 + wid;
    if (n >= N_NODES) return;
    const int rs = rowstart[n];
    const int dg = deg[n];
    const int re = rs + dg;
    const int re8 = rs + ((dg + 7) & ~7);
    const float adv = a2d[n];
    for (int i = rs + lane; i < re8; i += 64) {
        if (i < re) {
            int s = csr[i];
            ew2[i] = expf(lrelu(a2s[s] + adv));
        } else {
            ew2[i] = 0.f;
        }
    }
}

// ---------------- layer2 gather: bf16 rows, 8 edges/iter ----------------
__global__ __launch_bounds__(256) void k_l2_gather(
    const int* __restrict__ rowstart, const int* __restrict__ csr,
    const int* __restrict__ deg, const float* __restrict__ ew2,
    const unsigned short* __restrict__ xwbf, float* __restrict__ h2) {
    const int lane = threadIdx.x & 63;
    const int wid = threadIdx.x >> 6;
    const int n = blockIdx.x * 4 + wid;
    if (n >= N_NODES) return;
    const int rs = rowstart[n];
    const int nb8 = (deg[n] + 7) >> 3;
    const int4* c4 = (const int4*)(csr + rs);
    const float4* w4 = (const float4*)(ew2 + rs);
    float den = 0.f, acc = 0.f;
    for (int b = 0; b < nb8; ++b) {
        int4 sA = c4[2 * b], sB = c4[2 * b + 1];
        float4 wA = w4[2 * b], wB = w4[2 * b + 1];
        float v0 = bf2f(xwbf[(size_t)sA.x * F2 + lane]);
        float v1 = bf2f(xwbf[(size_t)sA.y * F2 + lane]);
        float v2 = bf2f(xwbf[(size_t)sA.z * F2 + lane]);
        float v3 = bf2f(xwbf[(size_t)sA.w * F2 + lane]);
        float v4 = bf2f(xwbf[(size_t)sB.x * F2 + lane]);
        float v5 = bf2f(xwbf[(size_t)sB.y * F2 + lane]);
        float v6 = bf2f(xwbf[(size_t)sB.z * F2 + lane]);
        float v7 = bf2f(xwbf[(size_t)sB.w * F2 + lane]);
        den += ((wA.x + wA.y) + (wA.z + wA.w)) + ((wB.x + wB.y) + (wB.z + wB.w));
        acc = fmaf(wA.x, v0, fmaf(wA.y, v1, fmaf(wA.z, v2, fmaf(wA.w, v3, acc))));
        acc = fmaf(wB.x, v4, fmaf(wB.y, v5, fmaf(wB.z, v6, fmaf(wB.w, v7, acc))));
    }
    h2[(size_t)n * F2 + lane] = acc / (den + EPS_F);
}

// ---------------- mean over nodes (fp64 accum) ----------------
#define MEAN_BLOCKS 256
__global__ __launch_bounds__(256) void k_mean(const float* __restrict__ h2,
                                              double* __restrict__ accum) {
    const int t = threadIdx.x;
    const int c = t & 63;
    double acc = 0.0;
    const size_t total = (size_t)N_NODES * F2;
    for (size_t idx = (size_t)blockIdx.x * 256 + t; idx < total; idx += (size_t)MEAN_BLOCKS * 256)
        acc += (double)h2[idx];
    __shared__ double red[256];
    red[t] = acc;
    __syncthreads();
    if (t < 64) {
        double v = red[t] + red[t + 64] + red[t + 128] + red[t + 192];
        atomicAdd(&accum[c], v);
    }
}

__global__ void k_final(const double* __restrict__ accum, const float* __restrict__ b2,
                        float* __restrict__ out) {
    int t = threadIdx.x;
    if (t < F2) out[t] = (float)(accum[t] * (1.0 / (double)N_NODES)) + b2[t];
}

// ---------------- launch ----------------
extern "C" void kernel_launch(void* const* d_in, const int* in_sizes, int n_in,
                              void* d_out, int out_size, void* d_ws, size_t ws_size,
                              hipStream_t stream) {
    (void)in_sizes; (void)n_in; (void)out_size; (void)ws_size;
    const float* x   = (const float*)d_in[0];
    const int*   ei  = (const int*)d_in[1];
    const float* W1  = (const float*)d_in[2];
    const float* as1 = (const float*)d_in[3];
    const float* ad1 = (const float*)d_in[4];
    const float* b1  = (const float*)d_in[5];
    const float* W2  = (const float*)d_in[6];
    const float* as2 = (const float*)d_in[7];
    const float* ad2 = (const float*)d_in[8];
    const float* b2  = (const float*)d_in[9];
    float* out = (float*)d_out;

    char* ws = (char*)d_ws;
    size_t off = 0;
    auto alloc = [&](size_t bytes) -> void* {
        void* p = ws + off;
        off += (bytes + 255) & ~(size_t)255;
        return p;
    };
    unsigned short* xw1bf = (unsigned short*)alloc((size_t)N_NODES * F1 * 2);
    float* h1       = (float*)alloc((size_t)N_NODES * F1 * 4);
    unsigned short* xw2bf = (unsigned short*)alloc((size_t)N_NODES * F2 * 2);
    float* h2       = (float*)alloc((size_t)N_NODES * F2 * 4);
    float* ew1      = (float*)alloc((size_t)H1 * TEP * 4);
    float* ew2      = (float*)alloc((size_t)TEP * 4);
    float* a1s      = (float*)alloc((size_t)N_NODES * H1 * 4);
    float* a1d      = (float*)alloc((size_t)N_NODES * H1 * 4);
    float* a2s      = (float*)alloc((size_t)N_NODES * 4);
    float* a2d      = (float*)alloc((size_t)N_NODES * 4);
    int*   deg      = (int*)alloc((size_t)N_NODES * 4);
    int*   cursor   = (int*)alloc((size_t)N_NODES * 4);
    int*   rowstart = (int*)alloc((size_t)(N_NODES + 1) * 4);
    int*   csr      = (int*)alloc((size_t)TEP * 4);
    int*   incl     = (int*)alloc((size_t)N_NODES * 4);
    int*   bsum     = (int*)alloc(64 * 4);
    double* accum   = (double*)alloc(F2 * 8);

    const int nscan = (N_NODES + 1023) / 1024;  // 49
    const int nwave4 = (N_NODES + 3) / 4;       // 12500

    k_init<<<(N_NODES + 255) / 256, 256, 0, stream>>>(deg, cursor, (unsigned long long*)accum);
    k_l1_mm<<<N_NODES / 16, 256, 0, stream>>>(x, W1, as1, ad1, xw1bf, a1s, a1d);
    k_deg<<<(TE + 255) / 256, 256, 0, stream>>>(ei, deg);
    k_scan1<<<nscan, 1024, 0, stream>>>(deg, incl, bsum);
    k_scan2<<<1, 64, 0, stream>>>(bsum, nscan);
    k_scan3<<<nscan, 1024, 0, stream>>>(incl, bsum, rowstart);
    k_scatter<<<(TE + 255) / 256, 256, 0, stream>>>(ei, rowstart, cursor, csr);
    k_ew1<<<nwave4, 256, 0, stream>>>(rowstart, csr, deg, a1s, a1d, ew1);
    k_l1_gather<<<nwave4, 256, 0, stream>>>(rowstart, csr, deg, ew1, xw1bf, b1, h1);
    k_l2_mm<<<N_NODES / 16, 256, 0, stream>>>(h1, W2, as2, ad2, xw2bf, a2s, a2d);
    k_ew2<<<nwave4, 256, 0, stream>>>(rowstart, csr, deg, a2s, a2d, ew2);
    k_l2_gather<<<nwave4, 256, 0, stream>>>(rowstart, csr, deg, ew2, xw2bf, h2);
    k_mean<<<MEAN_BLOCKS, 256, 0, stream>>>(h2, accum);
    k_final<<<1, 64, 0, stream>>>(accum, b2, out);
}

// Round 7
// 438.302 us; speedup vs baseline: 1.4294x; 1.0746x over previous
//
#include <hip/hip_runtime.h>
#include <math.h>

#define N_NODES 50000
#define E_RAW   1600000
#define TE      (E_RAW + N_NODES)     // 1650000 edges incl. self loops
#define TEP     (TE + 8 * N_NODES)    // CSR padded to 8-aligned rows (upper bound)
#define F_IN    128
#define H1      4
#define F1      128                   // H1*C1
#define F2      64
#define NEG_SLOPE 0.2f
#define EPS_F   1e-16f

__device__ __forceinline__ float lrelu(float v) { return v > 0.f ? v : NEG_SLOPE * v; }

// bf16 round-to-nearest-even pack/unpack (values here are tame: no NaN/Inf)
__device__ __forceinline__ unsigned short f2bf(float f) {
    unsigned u = __float_as_uint(f);
    return (unsigned short)((u + 0x7fffu + ((u >> 16) & 1u)) >> 16);
}
__device__ __forceinline__ float2 bfpair2f(unsigned u) {
    float2 r;
    r.x = __uint_as_float(u << 16);          // low ushort  = even channel
    r.y = __uint_as_float(u & 0xffff0000u);  // high ushort = odd channel
    return r;
}
__device__ __forceinline__ float bf2f(unsigned short s) {
    return __uint_as_float(((unsigned)s) << 16);
}

// ---------------- init: zero deg, accum ----------------
__global__ void k_init(int* __restrict__ deg, unsigned long long* __restrict__ accum) {
    int i = blockIdx.x * blockDim.x + threadIdx.x;
    if (i < N_NODES) deg[i] = 0;
    if (i < F2) accum[i] = 0ULL;
}

// ---------------- layer1 matmul + attention coefs ----------------
// 16 nodes/block, 256 threads: c = t&127 (channel), p = t>>7 (node half, 8 nodes).
// xw stored bf16 (gather table); attention coefs fp32-exact from registers.
// #pragma unroll 2: full unroll -> 256 VGPR cliff (round 4).
__global__ __launch_bounds__(256) void k_l1_mm(
    const float* __restrict__ x, const float* __restrict__ W,
    const float* __restrict__ atts, const float* __restrict__ attd,
    unsigned short* __restrict__ xwbf, float* __restrict__ a1s, float* __restrict__ a1d) {
    const int t = threadIdx.x;
    const int c = t & 127;
    const int p = t >> 7;
    const int n0 = blockIdx.x * 16;    // 50000 = 16*3125, no tail
    __shared__ float xs[16][F_IN];
    {
        const float4* src = (const float4*)(x + (size_t)n0 * F_IN);
        float4* dstv = (float4*)&xs[0][0];
        dstv[t] = src[t];
        dstv[t + 256] = src[t + 256];
    }
    __syncthreads();
    float acc[8];
#pragma unroll
    for (int j = 0; j < 8; ++j) acc[j] = 0.f;
    const float* xsp = &xs[p * 8][0];
#pragma unroll 2
    for (int k4 = 0; k4 < F_IN / 4; ++k4) {
        int k = k4 * 4;
        float w0 = W[(k + 0) * F1 + c];
        float w1 = W[(k + 1) * F1 + c];
        float w2 = W[(k + 2) * F1 + c];
        float w3 = W[(k + 3) * F1 + c];
#pragma unroll
        for (int j = 0; j < 8; ++j) {
            float4 xv = ((const float4*)(xsp + j * F_IN))[k4];
            acc[j] = fmaf(xv.x, w0, fmaf(xv.y, w1, fmaf(xv.z, w2, fmaf(xv.w, w3, acc[j]))));
        }
    }
    float ats = atts[c], atd = attd[c];
#pragma unroll
    for (int j = 0; j < 8; ++j) {
        int n = n0 + p * 8 + j;
        xwbf[(size_t)n * F1 + c] = f2bf(acc[j]);
        float ps = acc[j] * ats, pd = acc[j] * atd;
#pragma unroll
        for (int off = 16; off; off >>= 1) {
            ps += __shfl_down(ps, off, 32);
            pd += __shfl_down(pd, off, 32);
        }
        if ((t & 31) == 0) {
            int h = (c >> 5);
            a1s[n * H1 + h] = ps;
            a1d[n * H1 + h] = pd;
        }
    }
}

// ---------------- degree count + per-edge position ----------------
__global__ void k_deg(const int* __restrict__ ei, int* __restrict__ deg,
                      int* __restrict__ epos) {
    int e = blockIdx.x * blockDim.x + threadIdx.x;
    if (e >= TE) return;
    int d = (e < E_RAW) ? ei[E_RAW + e] : (e - E_RAW);
    epos[e] = atomicAdd(&deg[d], 1);
}

// ---------------- exclusive scan over 8-PADDED degrees (2-level) --------------
__global__ __launch_bounds__(1024) void k_scan1(const int* __restrict__ deg,
                                                int* __restrict__ incl, int* __restrict__ bsum) {
    int t = threadIdx.x, g = blockIdx.x;
    int idx = g * 1024 + t;
    int v = (idx < N_NODES) ? ((deg[idx] + 7) & ~7) : 0;
    int lane = t & 63, w = t >> 6;
#pragma unroll
    for (int off = 1; off < 64; off <<= 1) {
        int u = __shfl_up(v, off, 64);
        if (lane >= off) v += u;
    }
    __shared__ int ws[16];
    if (lane == 63) ws[w] = v;
    __syncthreads();
    if (w == 0 && lane < 16) {
        int s = ws[lane];
#pragma unroll
        for (int off = 1; off < 16; off <<= 1) {
            int u = __shfl_up(s, off, 16);
            if (lane >= off) s += u;
        }
        ws[lane] = s;
    }
    __syncthreads();
    if (w > 0) v += ws[w - 1];
    if (idx < N_NODES) incl[idx] = v;
    if (t == 1023) bsum[g] = v;
}

__global__ void k_scan2(int* __restrict__ bsum, int nblk) {
    int t = threadIdx.x;
    int v = (t < nblk) ? bsum[t] : 0;
#pragma unroll
    for (int off = 1; off < 64; off <<= 1) {
        int u = __shfl_up(v, off, 64);
        if (t >= off) v += u;
    }
    if (t < nblk) bsum[t] = v;
}

__global__ __launch_bounds__(1024) void k_scan3(const int* __restrict__ incl,
                                                const int* __restrict__ bsum,
                                                int* __restrict__ rowstart) {
    int idx = blockIdx.x * 1024 + threadIdx.x;
    if (idx >= N_NODES) return;
    int off = (blockIdx.x > 0) ? bsum[blockIdx.x - 1] : 0;
    rowstart[idx + 1] = incl[idx] + off;
    if (idx == 0) rowstart[0] = 0;
}

// ---------------- scatter into padded CSR (no atomics; nt store) -------------
__global__ void k_scatter(const int* __restrict__ ei, const int* __restrict__ rowstart,
                          const int* __restrict__ epos, int* __restrict__ csr) {
    int e = blockIdx.x * blockDim.x + threadIdx.x;
    if (e >= TE) return;
    int s, d;
    if (e < E_RAW) { s = ei[e]; d = ei[E_RAW + e]; }
    else { s = e - E_RAW; d = s; }
    int pos = rowstart[d] + epos[e];
    __builtin_nontemporal_store(s, &csr[pos]);
}

// ---------------- layer1 edge weights + pad zero-fill ----------------
__global__ __launch_bounds__(256) void k_ew1(
    const int* __restrict__ rowstart, int* __restrict__ csr, const int* __restrict__ deg,
    const float* __restrict__ a1s, const float* __restrict__ a1d,
    float* __restrict__ ew1) {
    const int lane = threadIdx.x & 63;
    const int wid = threadIdx.x >> 6;
    const int n = blockIdx.x * 4 + wid;
    if (n >= N_NODES) return;
    const int rs = rowstart[n];
    const int dg = deg[n];
    const int re = rs + dg;
    const int re8 = rs + ((dg + 7) & ~7);
    const float4 ad = ((const float4*)a1d)[n];
    for (int i = rs + lane; i < re8; i += 64) {
        if (i < re) {
            int s = csr[i];
            float4 as = ((const float4*)a1s)[s];
            ew1[0 * TEP + i] = expf(lrelu(as.x + ad.x));
            ew1[1 * TEP + i] = expf(lrelu(as.y + ad.y));
            ew1[2 * TEP + i] = expf(lrelu(as.z + ad.z));
            ew1[3 * TEP + i] = expf(lrelu(as.w + ad.w));
        } else {
            csr[i] = 0;
            ew1[0 * TEP + i] = 0.f;
            ew1[1 * TEP + i] = 0.f;
            ew1[2 * TEP + i] = 0.f;
            ew1[3 * TEP + i] = 0.f;
        }
    }
}

// ---------------- layer1 gather: bf16 rows, 8 edges/iter ----------------
__global__ __launch_bounds__(256) void k_l1_gather(
    const int* __restrict__ rowstart, const int* __restrict__ csr,
    const int* __restrict__ deg, const float* __restrict__ ew1,
    const unsigned short* __restrict__ xwbf, const float* __restrict__ b1,
    float* __restrict__ h1) {
    const int lane = threadIdx.x & 63;
    const int wid = threadIdx.x >> 6;
    const int n = blockIdx.x * 4 + wid;
    if (n >= N_NODES) return;
    const int rs = rowstart[n];
    const int nb8 = (deg[n] + 7) >> 3;
    const int h = lane >> 4;
    const int4* c4 = (const int4*)(csr + rs);
    const float4* w4 = (const float4*)(ew1 + h * TEP + rs);
    const unsigned* xwv = (const unsigned*)xwbf;   // 1 uint = 2 bf16 channels
    float den = 0.f, ax = 0.f, ay = 0.f;
    for (int b = 0; b < nb8; ++b) {
        int4 sA = c4[2 * b], sB = c4[2 * b + 1];
        float4 wA = w4[2 * b], wB = w4[2 * b + 1];
        unsigned u0 = xwv[sA.x * 64 + lane], u1 = xwv[sA.y * 64 + lane];
        unsigned u2 = xwv[sA.z * 64 + lane], u3 = xwv[sA.w * 64 + lane];
        unsigned u4 = xwv[sB.x * 64 + lane], u5 = xwv[sB.y * 64 + lane];
        unsigned u6 = xwv[sB.z * 64 + lane], u7 = xwv[sB.w * 64 + lane];
        float2 v0 = bfpair2f(u0), v1 = bfpair2f(u1), v2 = bfpair2f(u2), v3 = bfpair2f(u3);
        float2 v4 = bfpair2f(u4), v5 = bfpair2f(u5), v6 = bfpair2f(u6), v7 = bfpair2f(u7);
        den += ((wA.x + wA.y) + (wA.z + wA.w)) + ((wB.x + wB.y) + (wB.z + wB.w));
        ax = fmaf(wA.x, v0.x, fmaf(wA.y, v1.x, fmaf(wA.z, v2.x, fmaf(wA.w, v3.x, ax))));
        ay = fmaf(wA.x, v0.y, fmaf(wA.y, v1.y, fmaf(wA.z, v2.y, fmaf(wA.w, v3.y, ay))));
        ax = fmaf(wB.x, v4.x, fmaf(wB.y, v5.x, fmaf(wB.z, v6.x, fmaf(wB.w, v7.x, ax))));
        ay = fmaf(wB.x, v4.y, fmaf(wB.y, v5.y, fmaf(wB.z, v6.y, fmaf(wB.w, v7.y, ay))));
    }
    const float inv = 1.f / (den + EPS_F);
    const int c0 = 2 * lane;
    float o0 = fmaf(ax, inv, b1[c0]);
    float o1 = fmaf(ay, inv, b1[c0 + 1]);
    o0 = o0 > 0.f ? o0 : expm1f(o0);
    o1 = o1 > 0.f ? o1 : expm1f(o1);
    ((float2*)h1)[(size_t)n * 64 + lane] = make_float2(o0, o1);
}

// ---------------- layer2 matmul + attention coefs ----------------
// 16 nodes/block, 256 threads: c = t&63, p = t>>6 (4 nodes each). xw2 bf16.
__global__ __launch_bounds__(256) void k_l2_mm(
    const float* __restrict__ h1, const float* __restrict__ W,
    const float* __restrict__ atts, const float* __restrict__ attd,
    unsigned short* __restrict__ xwbf, float* __restrict__ a2s, float* __restrict__ a2d) {
    const int t = threadIdx.x;
    const int c = t & 63;
    const int p = t >> 6;
    const int n0 = blockIdx.x * 16;    // 3125 blocks
    __shared__ float xs[16][F1];
    {
        const float4* src = (const float4*)(h1 + (size_t)n0 * F1);
        float4* dstv = (float4*)&xs[0][0];
        dstv[t] = src[t];
        dstv[t + 256] = src[t + 256];
    }
    __syncthreads();
    float acc[4];
#pragma unroll
    for (int j = 0; j < 4; ++j) acc[j] = 0.f;
    const float* xsp = &xs[p * 4][0];
#pragma unroll 2
    for (int k4 = 0; k4 < F1 / 4; ++k4) {
        int k = k4 * 4;
        float w0 = W[(k + 0) * F2 + c];
        float w1 = W[(k + 1) * F2 + c];
        float w2 = W[(k + 2) * F2 + c];
        float w3 = W[(k + 3) * F2 + c];
#pragma unroll
        for (int j = 0; j < 4; ++j) {
            float4 xv = ((const float4*)(xsp + j * F1))[k4];
            acc[j] = fmaf(xv.x, w0, fmaf(xv.y, w1, fmaf(xv.z, w2, fmaf(xv.w, w3, acc[j]))));
        }
    }
    float ats = atts[c], atd = attd[c];
#pragma unroll
    for (int j = 0; j < 4; ++j) {
        int n = n0 + p * 4 + j;
        xwbf[(size_t)n * F2 + c] = f2bf(acc[j]);
        float ps = acc[j] * ats, pd = acc[j] * atd;
#pragma unroll
        for (int off = 32; off; off >>= 1) {
            ps += __shfl_down(ps, off, 64);
            pd += __shfl_down(pd, off, 64);
        }
        if (c == 0) { a2s[n] = ps; a2d[n] = pd; }
    }
}

// ---------------- layer2 edge weights ----------------
__global__ __launch_bounds__(256) void k_ew2(
    const int* __restrict__ rowstart, const int* __restrict__ csr,
    const int* __restrict__ deg,
    const float* __restrict__ a2s, const float* __restrict__ a2d,
    float* __restrict__ ew2) {
    const int lane = threadIdx.x & 63;
    const int wid = threadIdx.x >> 6;
    const int n = blockIdx.x * 4 + wid;
    if (n >= N_NODES) return;
    const int rs = rowstart[n];
    const int dg = deg[n];
    const int re = rs + dg;
    const int re8 = rs + ((dg + 7) & ~7);
    const float adv = a2d[n];
    for (int i = rs + lane; i < re8; i += 64) {
        if (i < re) {
            int s = csr[i];
            ew2[i] = expf(lrelu(a2s[s] + adv));
        } else {
            ew2[i] = 0.f;
        }
    }
}

// ---------------- layer2 gather: bf16 rows, 8 edges/iter ----------------
__global__ __launch_bounds__(256) void k_l2_gather(
    const int* __restrict__ rowstart, const int* __restrict__ csr,
    const int* __restrict__ deg, const float* __restrict__ ew2,
    const unsigned short* __restrict__ xwbf, float* __restrict__ h2) {
    const int lane = threadIdx.x & 63;
    const int wid = threadIdx.x >> 6;
    const int n = blockIdx.x * 4 + wid;
    if (n >= N_NODES) return;
    const int rs = rowstart[n];
    const int nb8 = (deg[n] + 7) >> 3;
    const int4* c4 = (const int4*)(csr + rs);
    const float4* w4 = (const float4*)(ew2 + rs);
    float den = 0.f, acc = 0.f;
    for (int b = 0; b < nb8; ++b) {
        int4 sA = c4[2 * b], sB = c4[2 * b + 1];
        float4 wA = w4[2 * b], wB = w4[2 * b + 1];
        float v0 = bf2f(xwbf[(size_t)sA.x * F2 + lane]);
        float v1 = bf2f(xwbf[(size_t)sA.y * F2 + lane]);
        float v2 = bf2f(xwbf[(size_t)sA.z * F2 + lane]);
        float v3 = bf2f(xwbf[(size_t)sA.w * F2 + lane]);
        float v4 = bf2f(xwbf[(size_t)sB.x * F2 + lane]);
        float v5 = bf2f(xwbf[(size_t)sB.y * F2 + lane]);
        float v6 = bf2f(xwbf[(size_t)sB.z * F2 + lane]);
        float v7 = bf2f(xwbf[(size_t)sB.w * F2 + lane]);
        den += ((wA.x + wA.y) + (wA.z + wA.w)) + ((wB.x + wB.y) + (wB.z + wB.w));
        acc = fmaf(wA.x, v0, fmaf(wA.y, v1, fmaf(wA.z, v2, fmaf(wA.w, v3, acc))));
        acc = fmaf(wB.x, v4, fmaf(wB.y, v5, fmaf(wB.z, v6, fmaf(wB.w, v7, acc))));
    }
    h2[(size_t)n * F2 + lane] = acc / (den + EPS_F);
}

// ---------------- mean over nodes (fp64 accum) ----------------
#define MEAN_BLOCKS 256
__global__ __launch_bounds__(256) void k_mean(const float* __restrict__ h2,
                                              double* __restrict__ accum) {
    const int t = threadIdx.x;
    const int c = t & 63;
    double acc = 0.0;
    const size_t total = (size_t)N_NODES * F2;
    for (size_t idx = (size_t)blockIdx.x * 256 + t; idx < total; idx += (size_t)MEAN_BLOCKS * 256)
        acc += (double)h2[idx];
    __shared__ double red[256];
    red[t] = acc;
    __syncthreads();
    if (t < 64) {
        double v = red[t] + red[t + 64] + red[t + 128] + red[t + 192];
        atomicAdd(&accum[c], v);
    }
}

__global__ void k_final(const double* __restrict__ accum, const float* __restrict__ b2,
                        float* __restrict__ out) {
    int t = threadIdx.x;
    if (t < F2) out[t] = (float)(accum[t] * (1.0 / (double)N_NODES)) + b2[t];
}

// ---------------- launch ----------------
extern "C" void kernel_launch(void* const* d_in, const int* in_sizes, int n_in,
                              void* d_out, int out_size, void* d_ws, size_t ws_size,
                              hipStream_t stream) {
    (void)in_sizes; (void)n_in; (void)out_size; (void)ws_size;
    const float* x   = (const float*)d_in[0];
    const int*   ei  = (const int*)d_in[1];
    const float* W1  = (const float*)d_in[2];
    const float* as1 = (const float*)d_in[3];
    const float* ad1 = (const float*)d_in[4];
    const float* b1  = (const float*)d_in[5];
    const float* W2  = (const float*)d_in[6];
    const float* as2 = (const float*)d_in[7];
    const float* ad2 = (const float*)d_in[8];
    const float* b2  = (const float*)d_in[9];
    float* out = (float*)d_out;

    char* ws = (char*)d_ws;
    size_t off = 0;
    auto alloc = [&](size_t bytes) -> void* {
        void* p = ws + off;
        off += (bytes + 255) & ~(size_t)255;
        return p;
    };
    unsigned short* xw1bf = (unsigned short*)alloc((size_t)N_NODES * F1 * 2);
    float* h1       = (float*)alloc((size_t)N_NODES * F1 * 4);
    unsigned short* xw2bf = (unsigned short*)alloc((size_t)N_NODES * F2 * 2);
    float* h2       = (float*)alloc((size_t)N_NODES * F2 * 4);
    float* ew1      = (float*)alloc((size_t)H1 * TEP * 4);
    float* ew2      = (float*)alloc((size_t)TEP * 4);
    float* a1s      = (float*)alloc((size_t)N_NODES * H1 * 4);
    float* a1d      = (float*)alloc((size_t)N_NODES * H1 * 4);
    float* a2s      = (float*)alloc((size_t)N_NODES * 4);
    float* a2d      = (float*)alloc((size_t)N_NODES * 4);
    int*   deg      = (int*)alloc((size_t)N_NODES * 4);
    int*   epos     = (int*)alloc((size_t)TE * 4);
    int*   rowstart = (int*)alloc((size_t)(N_NODES + 1) * 4);
    int*   csr      = (int*)alloc((size_t)TEP * 4);
    int*   incl     = (int*)alloc((size_t)N_NODES * 4);
    int*   bsum     = (int*)alloc(64 * 4);
    double* accum   = (double*)alloc(F2 * 8);

    const int nscan = (N_NODES + 1023) / 1024;  // 49
    const int nwave4 = (N_NODES + 3) / 4;       // 12500

    k_init<<<(N_NODES + 255) / 256, 256, 0, stream>>>(deg, (unsigned long long*)accum);
    k_l1_mm<<<N_NODES / 16, 256, 0, stream>>>(x, W1, as1, ad1, xw1bf, a1s, a1d);
    k_deg<<<(TE + 255) / 256, 256, 0, stream>>>(ei, deg, epos);
    k_scan1<<<nscan, 1024, 0, stream>>>(deg, incl, bsum);
    k_scan2<<<1, 64, 0, stream>>>(bsum, nscan);
    k_scan3<<<nscan, 1024, 0, stream>>>(incl, bsum, rowstart);
    k_scatter<<<(TE + 255) / 256, 256, 0, stream>>>(ei, rowstart, epos, csr);
    k_ew1<<<nwave4, 256, 0, stream>>>(rowstart, csr, deg, a1s, a1d, ew1);
    k_l1_gather<<<nwave4, 256, 0, stream>>>(rowstart, csr, deg, ew1, xw1bf, b1, h1);
    k_l2_mm<<<N_NODES / 16, 256, 0, stream>>>(h1, W2, as2, ad2, xw2bf, a2s, a2d);
    k_ew2<<<nwave4, 256, 0, stream>>>(rowstart, csr, deg, a2s, a2d, ew2);
    k_l2_gather<<<nwave4, 256, 0, stream>>>(rowstart, csr, deg, ew2, xw2bf, h2);
    k_mean<<<MEAN_BLOCKS, 256, 0, stream>>>(h2, accum);
    k_final<<<1, 64, 0, stream>>>(accum, b2, out);
}

// Round 8
// 430.673 us; speedup vs baseline: 1.4547x; 1.0177x over previous
//
#include <hip/hip_runtime.h>
#include <math.h>

#define N_NODES 50000
#define E_RAW   1600000
#define TE      (E_RAW + N_NODES)     // 1650000 edges incl. self loops
#define TEP     (TE + 8 * N_NODES)    // CSR padded to 8-aligned rows (upper bound)
#define F_IN    128
#define H1      4
#define F1      128                   // H1*C1
#define F2      64
#define NEG_SLOPE 0.2f
#define EPS_F   1e-16f
#define NPART   8
// edge -> counter partition; pure function of e so k_deg/k_scatter agree
#define EPART(e) (((e) >> 8) & (NPART - 1))

__device__ __forceinline__ float lrelu(float v) { return v > 0.f ? v : NEG_SLOPE * v; }

// bf16 round-to-nearest-even pack/unpack (values here are tame: no NaN/Inf)
__device__ __forceinline__ unsigned short f2bf(float f) {
    unsigned u = __float_as_uint(f);
    return (unsigned short)((u + 0x7fffu + ((u >> 16) & 1u)) >> 16);
}
__device__ __forceinline__ float2 bfpair2f(unsigned u) {
    float2 r;
    r.x = __uint_as_float(u << 16);          // low ushort  = even channel
    r.y = __uint_as_float(u & 0xffff0000u);  // high ushort = odd channel
    return r;
}
__device__ __forceinline__ float bf2f(unsigned short s) {
    return __uint_as_float(((unsigned)s) << 16);
}

// ---------------- layer1 matmul + attention coefs ----------------
// 16 nodes/block, 256 threads: c = t&127 (channel), p = t>>7 (node half, 8 nodes).
// xw stored bf16 (gather table); attention coefs fp32-exact from registers.
// #pragma unroll 2: full unroll -> 256 VGPR cliff (round 4).
__global__ __launch_bounds__(256) void k_l1_mm(
    const float* __restrict__ x, const float* __restrict__ W,
    const float* __restrict__ atts, const float* __restrict__ attd,
    unsigned short* __restrict__ xwbf, float* __restrict__ a1s, float* __restrict__ a1d) {
    const int t = threadIdx.x;
    const int c = t & 127;
    const int p = t >> 7;
    const int n0 = blockIdx.x * 16;    // 50000 = 16*3125, no tail
    __shared__ float xs[16][F_IN];
    {
        const float4* src = (const float4*)(x + (size_t)n0 * F_IN);
        float4* dstv = (float4*)&xs[0][0];
        dstv[t] = src[t];
        dstv[t + 256] = src[t + 256];
    }
    __syncthreads();
    float acc[8];
#pragma unroll
    for (int j = 0; j < 8; ++j) acc[j] = 0.f;
    const float* xsp = &xs[p * 8][0];
#pragma unroll 2
    for (int k4 = 0; k4 < F_IN / 4; ++k4) {
        int k = k4 * 4;
        float w0 = W[(k + 0) * F1 + c];
        float w1 = W[(k + 1) * F1 + c];
        float w2 = W[(k + 2) * F1 + c];
        float w3 = W[(k + 3) * F1 + c];
#pragma unroll
        for (int j = 0; j < 8; ++j) {
            float4 xv = ((const float4*)(xsp + j * F_IN))[k4];
            acc[j] = fmaf(xv.x, w0, fmaf(xv.y, w1, fmaf(xv.z, w2, fmaf(xv.w, w3, acc[j]))));
        }
    }
    float ats = atts[c], atd = attd[c];
#pragma unroll
    for (int j = 0; j < 8; ++j) {
        int n = n0 + p * 8 + j;
        xwbf[(size_t)n * F1 + c] = f2bf(acc[j]);
        float ps = acc[j] * ats, pd = acc[j] * atd;
#pragma unroll
        for (int off = 16; off; off >>= 1) {
            ps += __shfl_down(ps, off, 32);
            pd += __shfl_down(pd, off, 32);
        }
        if ((t & 31) == 0) {
            int h = (c >> 5);
            a1s[n * H1 + h] = ps;
            a1d[n * H1 + h] = pd;
        }
    }
}

// ---------------- degree count (8-way split counters) + per-edge position ----
__global__ void k_deg(const int* __restrict__ ei, int* __restrict__ deg8,
                      int* __restrict__ epos) {
    int e = blockIdx.x * blockDim.x + threadIdx.x;
    if (e >= TE) return;
    int d = (e < E_RAW) ? ei[E_RAW + e] : (e - E_RAW);
    int p = EPART(e);
    int r = atomicAdd(&deg8[p * N_NODES + d], 1);
    __builtin_nontemporal_store(r, &epos[e]);
}

// ---------------- scan1: fold 8 partitions -> deg, part_off; scan 8-padded ---
__global__ __launch_bounds__(1024) void k_scan1(const int* __restrict__ deg8,
                                                int* __restrict__ deg,
                                                int* __restrict__ part_off,
                                                int* __restrict__ incl, int* __restrict__ bsum) {
    int t = threadIdx.x, g = blockIdx.x;
    int idx = g * 1024 + t;
    int v = 0;
    if (idx < N_NODES) {
        int run = 0;
#pragma unroll
        for (int p = 0; p < NPART; ++p) {
            part_off[p * N_NODES + idx] = run;
            run += deg8[p * N_NODES + idx];
        }
        deg[idx] = run;
        v = (run + 7) & ~7;
    }
    int lane = t & 63, w = t >> 6;
#pragma unroll
    for (int off = 1; off < 64; off <<= 1) {
        int u = __shfl_up(v, off, 64);
        if (lane >= off) v += u;
    }
    __shared__ int ws[16];
    if (lane == 63) ws[w] = v;
    __syncthreads();
    if (w == 0 && lane < 16) {
        int s = ws[lane];
#pragma unroll
        for (int off = 1; off < 16; off <<= 1) {
            int u = __shfl_up(s, off, 16);
            if (lane >= off) s += u;
        }
        ws[lane] = s;
    }
    __syncthreads();
    if (w > 0) v += ws[w - 1];
    if (idx < N_NODES) incl[idx] = v;
    if (t == 1023) bsum[g] = v;
}

__global__ void k_scan2(int* __restrict__ bsum, int nblk) {
    int t = threadIdx.x;
    int v = (t < nblk) ? bsum[t] : 0;
#pragma unroll
    for (int off = 1; off < 64; off <<= 1) {
        int u = __shfl_up(v, off, 64);
        if (t >= off) v += u;
    }
    if (t < nblk) bsum[t] = v;
}

__global__ __launch_bounds__(1024) void k_scan3(const int* __restrict__ incl,
                                                const int* __restrict__ bsum,
                                                int* __restrict__ rowstart) {
    int idx = blockIdx.x * 1024 + threadIdx.x;
    if (idx >= N_NODES) return;
    int off = (blockIdx.x > 0) ? bsum[blockIdx.x - 1] : 0;
    rowstart[idx + 1] = incl[idx] + off;
    if (idx == 0) rowstart[0] = 0;
}

// ---------------- scatter into padded CSR (no atomics; nt store) -------------
__global__ void k_scatter(const int* __restrict__ ei, const int* __restrict__ rowstart,
                          const int* __restrict__ part_off, const int* __restrict__ epos,
                          int* __restrict__ csr) {
    int e = blockIdx.x * blockDim.x + threadIdx.x;
    if (e >= TE) return;
    int s, d;
    if (e < E_RAW) { s = ei[e]; d = ei[E_RAW + e]; }
    else { s = e - E_RAW; d = s; }
    int p = EPART(e);
    int pos = rowstart[d] + part_off[p * N_NODES + d] + epos[e];
    __builtin_nontemporal_store(s, &csr[pos]);
}

// ---------------- layer1 edge weights + pad zero-fill ----------------
__global__ __launch_bounds__(256) void k_ew1(
    const int* __restrict__ rowstart, int* __restrict__ csr, const int* __restrict__ deg,
    const float* __restrict__ a1s, const float* __restrict__ a1d,
    float* __restrict__ ew1) {
    const int lane = threadIdx.x & 63;
    const int wid = threadIdx.x >> 6;
    const int n = blockIdx.x * 4 + wid;
    if (n >= N_NODES) return;
    const int rs = rowstart[n];
    const int dg = deg[n];
    const int re = rs + dg;
    const int re8 = rs + ((dg + 7) & ~7);
    const float4 ad = ((const float4*)a1d)[n];
    for (int i = rs + lane; i < re8; i += 64) {
        if (i < re) {
            int s = csr[i];
            float4 as = ((const float4*)a1s)[s];
            ew1[0 * TEP + i] = expf(lrelu(as.x + ad.x));
            ew1[1 * TEP + i] = expf(lrelu(as.y + ad.y));
            ew1[2 * TEP + i] = expf(lrelu(as.z + ad.z));
            ew1[3 * TEP + i] = expf(lrelu(as.w + ad.w));
        } else {
            csr[i] = 0;
            ew1[0 * TEP + i] = 0.f;
            ew1[1 * TEP + i] = 0.f;
            ew1[2 * TEP + i] = 0.f;
            ew1[3 * TEP + i] = 0.f;
        }
    }
}

// ---------------- layer1 gather: bf16 rows, 8 edges/iter ----------------
__global__ __launch_bounds__(256) void k_l1_gather(
    const int* __restrict__ rowstart, const int* __restrict__ csr,
    const int* __restrict__ deg, const float* __restrict__ ew1,
    const unsigned short* __restrict__ xwbf, const float* __restrict__ b1,
    float* __restrict__ h1) {
    const int lane = threadIdx.x & 63;
    const int wid = threadIdx.x >> 6;
    const int n = blockIdx.x * 4 + wid;
    if (n >= N_NODES) return;
    const int rs = rowstart[n];
    const int nb8 = (deg[n] + 7) >> 3;
    const int h = lane >> 4;
    const int4* c4 = (const int4*)(csr + rs);
    const float4* w4 = (const float4*)(ew1 + h * TEP + rs);
    const unsigned* xwv = (const unsigned*)xwbf;   // 1 uint = 2 bf16 channels
    float den = 0.f, ax = 0.f, ay = 0.f;
    for (int b = 0; b < nb8; ++b) {
        int4 sA = c4[2 * b], sB = c4[2 * b + 1];
        float4 wA = w4[2 * b], wB = w4[2 * b + 1];
        unsigned u0 = xwv[sA.x * 64 + lane], u1 = xwv[sA.y * 64 + lane];
        unsigned u2 = xwv[sA.z * 64 + lane], u3 = xwv[sA.w * 64 + lane];
        unsigned u4 = xwv[sB.x * 64 + lane], u5 = xwv[sB.y * 64 + lane];
        unsigned u6 = xwv[sB.z * 64 + lane], u7 = xwv[sB.w * 64 + lane];
        float2 v0 = bfpair2f(u0), v1 = bfpair2f(u1), v2 = bfpair2f(u2), v3 = bfpair2f(u3);
        float2 v4 = bfpair2f(u4), v5 = bfpair2f(u5), v6 = bfpair2f(u6), v7 = bfpair2f(u7);
        den += ((wA.x + wA.y) + (wA.z + wA.w)) + ((wB.x + wB.y) + (wB.z + wB.w));
        ax = fmaf(wA.x, v0.x, fmaf(wA.y, v1.x, fmaf(wA.z, v2.x, fmaf(wA.w, v3.x, ax))));
        ay = fmaf(wA.x, v0.y, fmaf(wA.y, v1.y, fmaf(wA.z, v2.y, fmaf(wA.w, v3.y, ay))));
        ax = fmaf(wB.x, v4.x, fmaf(wB.y, v5.x, fmaf(wB.z, v6.x, fmaf(wB.w, v7.x, ax))));
        ay = fmaf(wB.x, v4.y, fmaf(wB.y, v5.y, fmaf(wB.z, v6.y, fmaf(wB.w, v7.y, ay))));
    }
    const float inv = 1.f / (den + EPS_F);
    const int c0 = 2 * lane;
    float o0 = fmaf(ax, inv, b1[c0]);
    float o1 = fmaf(ay, inv, b1[c0 + 1]);
    o0 = o0 > 0.f ? o0 : expm1f(o0);
    o1 = o1 > 0.f ? o1 : expm1f(o1);
    ((float2*)h1)[(size_t)n * 64 + lane] = make_float2(o0, o1);
}

// ---------------- layer2 matmul + attention coefs ----------------
// 16 nodes/block, 256 threads: c = t&63, p = t>>6 (4 nodes each). xw2 bf16.
__global__ __launch_bounds__(256) void k_l2_mm(
    const float* __restrict__ h1, const float* __restrict__ W,
    const float* __restrict__ atts, const float* __restrict__ attd,
    unsigned short* __restrict__ xwbf, float* __restrict__ a2s, float* __restrict__ a2d) {
    const int t = threadIdx.x;
    const int c = t & 63;
    const int p = t >> 6;
    const int n0 = blockIdx.x * 16;    // 3125 blocks
    __shared__ float xs[16][F1];
    {
        const float4* src = (const float4*)(h1 + (size_t)n0 * F1);
        float4* dstv = (float4*)&xs[0][0];
        dstv[t] = src[t];
        dstv[t + 256] = src[t + 256];
    }
    __syncthreads();
    float acc[4];
#pragma unroll
    for (int j = 0; j < 4; ++j) acc[j] = 0.f;
    const float* xsp = &xs[p * 4][0];
#pragma unroll 2
    for (int k4 = 0; k4 < F1 / 4; ++k4) {
        int k = k4 * 4;
        float w0 = W[(k + 0) * F2 + c];
        float w1 = W[(k + 1) * F2 + c];
        float w2 = W[(k + 2) * F2 + c];
        float w3 = W[(k + 3) * F2 + c];
#pragma unroll
        for (int j = 0; j < 4; ++j) {
            float4 xv = ((const float4*)(xsp + j * F1))[k4];
            acc[j] = fmaf(xv.x, w0, fmaf(xv.y, w1, fmaf(xv.z, w2, fmaf(xv.w, w3, acc[j]))));
        }
    }
    float ats = atts[c], atd = attd[c];
#pragma unroll
    for (int j = 0; j < 4; ++j) {
        int n = n0 + p * 4 + j;
        xwbf[(size_t)n * F2 + c] = f2bf(acc[j]);
        float ps = acc[j] * ats, pd = acc[j] * atd;
#pragma unroll
        for (int off = 32; off; off >>= 1) {
            ps += __shfl_down(ps, off, 64);
            pd += __shfl_down(pd, off, 64);
        }
        if (c == 0) { a2s[n] = ps; a2d[n] = pd; }
    }
}

// ---------------- layer2 edge weights ----------------
__global__ __launch_bounds__(256) void k_ew2(
    const int* __restrict__ rowstart, const int* __restrict__ csr,
    const int* __restrict__ deg,
    const float* __restrict__ a2s, const float* __restrict__ a2d,
    float* __restrict__ ew2) {
    const int lane = threadIdx.x & 63;
    const int wid = threadIdx.x >> 6;
    const int n = blockIdx.x * 4 + wid;
    if (n >= N_NODES) return;
    const int rs = rowstart[n];
    const int dg = deg[n];
    const int re = rs + dg;
    const int re8 = rs + ((dg + 7) & ~7);
    const float adv = a2d[n];
    for (int i = rs + lane; i < re8; i += 64) {
        if (i < re) {
            int s = csr[i];
            ew2[i] = expf(lrelu(a2s[s] + adv));
        } else {
            ew2[i] = 0.f;
        }
    }
}

// ---------------- layer2 gather: bf16 rows, 8 edges/iter ----------------
__global__ __launch_bounds__(256) void k_l2_gather(
    const int* __restrict__ rowstart, const int* __restrict__ csr,
    const int* __restrict__ deg, const float* __restrict__ ew2,
    const unsigned short* __restrict__ xwbf, float* __restrict__ h2) {
    const int lane = threadIdx.x & 63;
    const int wid = threadIdx.x >> 6;
    const int n = blockIdx.x * 4 + wid;
    if (n >= N_NODES) return;
    const int rs = rowstart[n];
    const int nb8 = (deg[n] + 7) >> 3;
    const int4* c4 = (const int4*)(csr + rs);
    const float4* w4 = (const float4*)(ew2 + rs);
    float den = 0.f, acc = 0.f;
    for (int b = 0; b < nb8; ++b) {
        int4 sA = c4[2 * b], sB = c4[2 * b + 1];
        float4 wA = w4[2 * b], wB = w4[2 * b + 1];
        float v0 = bf2f(xwbf[(size_t)sA.x * F2 + lane]);
        float v1 = bf2f(xwbf[(size_t)sA.y * F2 + lane]);
        float v2 = bf2f(xwbf[(size_t)sA.z * F2 + lane]);
        float v3 = bf2f(xwbf[(size_t)sA.w * F2 + lane]);
        float v4 = bf2f(xwbf[(size_t)sB.x * F2 + lane]);
        float v5 = bf2f(xwbf[(size_t)sB.y * F2 + lane]);
        float v6 = bf2f(xwbf[(size_t)sB.z * F2 + lane]);
        float v7 = bf2f(xwbf[(size_t)sB.w * F2 + lane]);
        den += ((wA.x + wA.y) + (wA.z + wA.w)) + ((wB.x + wB.y) + (wB.z + wB.w));
        acc = fmaf(wA.x, v0, fmaf(wA.y, v1, fmaf(wA.z, v2, fmaf(wA.w, v3, acc))));
        acc = fmaf(wB.x, v4, fmaf(wB.y, v5, fmaf(wB.z, v6, fmaf(wB.w, v7, acc))));
    }
    h2[(size_t)n * F2 + lane] = acc / (den + EPS_F);
}

// ---------------- mean over nodes (fp64 accum) ----------------
#define MEAN_BLOCKS 256
__global__ __launch_bounds__(256) void k_mean(const float* __restrict__ h2,
                                              double* __restrict__ accum) {
    const int t = threadIdx.x;
    const int c = t & 63;
    double acc = 0.0;
    const size_t total = (size_t)N_NODES * F2;
    for (size_t idx = (size_t)blockIdx.x * 256 + t; idx < total; idx += (size_t)MEAN_BLOCKS * 256)
        acc += (double)h2[idx];
    __shared__ double red[256];
    red[t] = acc;
    __syncthreads();
    if (t < 64) {
        double v = red[t] + red[t + 64] + red[t + 128] + red[t + 192];
        atomicAdd(&accum[c], v);
    }
}

__global__ void k_final(const double* __restrict__ accum, const float* __restrict__ b2,
                        float* __restrict__ out) {
    int t = threadIdx.x;
    if (t < F2) out[t] = (float)(accum[t] * (1.0 / (double)N_NODES)) + b2[t];
}

// ---------------- launch ----------------
extern "C" void kernel_launch(void* const* d_in, const int* in_sizes, int n_in,
                              void* d_out, int out_size, void* d_ws, size_t ws_size,
                              hipStream_t stream) {
    (void)in_sizes; (void)n_in; (void)out_size; (void)ws_size;
    const float* x   = (const float*)d_in[0];
    const int*   ei  = (const int*)d_in[1];
    const float* W1  = (const float*)d_in[2];
    const float* as1 = (const float*)d_in[3];
    const float* ad1 = (const float*)d_in[4];
    const float* b1  = (const float*)d_in[5];
    const float* W2  = (const float*)d_in[6];
    const float* as2 = (const float*)d_in[7];
    const float* ad2 = (const float*)d_in[8];
    const float* b2  = (const float*)d_in[9];
    float* out = (float*)d_out;

    char* ws = (char*)d_ws;
    size_t off = 0;
    auto alloc = [&](size_t bytes) -> void* {
        void* p = ws + off;
        off += (bytes + 255) & ~(size_t)255;
        return p;
    };
    unsigned short* xw1bf = (unsigned short*)alloc((size_t)N_NODES * F1 * 2);
    float* h1       = (float*)alloc((size_t)N_NODES * F1 * 4);
    unsigned short* xw2bf = (unsigned short*)alloc((size_t)N_NODES * F2 * 2);
    float* h2       = (float*)alloc((size_t)N_NODES * F2 * 4);
    float* ew1      = (float*)alloc((size_t)H1 * TEP * 4);
    float* ew2      = (float*)alloc((size_t)TEP * 4);
    float* a1s      = (float*)alloc((size_t)N_NODES * H1 * 4);
    float* a1d      = (float*)alloc((size_t)N_NODES * H1 * 4);
    float* a2s      = (float*)alloc((size_t)N_NODES * 4);
    float* a2d      = (float*)alloc((size_t)N_NODES * 4);
    int*   deg8     = (int*)alloc((size_t)NPART * N_NODES * 4);
    int*   deg      = (int*)alloc((size_t)N_NODES * 4);
    int*   part_off = (int*)alloc((size_t)NPART * N_NODES * 4);
    int*   epos     = (int*)alloc((size_t)TE * 4);
    int*   rowstart = (int*)alloc((size_t)(N_NODES + 1) * 4);
    int*   csr      = (int*)alloc((size_t)TEP * 4);
    int*   incl     = (int*)alloc((size_t)N_NODES * 4);
    int*   bsum     = (int*)alloc(64 * 4);
    double* accum   = (double*)alloc(F2 * 8);

    const int nscan = (N_NODES + 1023) / 1024;  // 49
    const int nwave4 = (N_NODES + 3) / 4;       // 12500

    hipMemsetAsync(deg8, 0, (size_t)NPART * N_NODES * 4, stream);
    hipMemsetAsync(accum, 0, F2 * 8, stream);
    k_l1_mm<<<N_NODES / 16, 256, 0, stream>>>(x, W1, as1, ad1, xw1bf, a1s, a1d);
    k_deg<<<(TE + 255) / 256, 256, 0, stream>>>(ei, deg8, epos);
    k_scan1<<<nscan, 1024, 0, stream>>>(deg8, deg, part_off, incl, bsum);
    k_scan2<<<1, 64, 0, stream>>>(bsum, nscan);
    k_scan3<<<nscan, 1024, 0, stream>>>(incl, bsum, rowstart);
    k_scatter<<<(TE + 255) / 256, 256, 0, stream>>>(ei, rowstart, part_off, epos, csr);
    k_ew1<<<nwave4, 256, 0, stream>>>(rowstart, csr, deg, a1s, a1d, ew1);
    k_l1_gather<<<nwave4, 256, 0, stream>>>(rowstart, csr, deg, ew1, xw1bf, b1, h1);
    k_l2_mm<<<N_NODES / 16, 256, 0, stream>>>(h1, W2, as2, ad2, xw2bf, a2s, a2d);
    k_ew2<<<nwave4, 256, 0, stream>>>(rowstart, csr, deg, a2s, a2d, ew2);
    k_l2_gather<<<nwave4, 256, 0, stream>>>(rowstart, csr, deg, ew2, xw2bf, h2);
    k_mean<<<MEAN_BLOCKS, 256, 0, stream>>>(h2, accum);
    k_final<<<1, 64, 0, stream>>>(accum, b2, out);
}